// Round 1
// baseline (421.982 us; speedup 1.0000x reference)
//
#include <hip/hip_runtime.h>
#include <math.h>

#define N_ENT 50000
#define N_REL 500
#define DEG 32
#define TOPK 10
#define H_DIM 256
#define N_HEADS 4
#define HEAD_DIM 64

// ---------------- workspace layout (bytes) ----------------
constexpr size_t OFF_SSRC0 = 0;                        // f64 [N_ENT]        400000
constexpr size_t OFF_SR0   = 400000;                   // f64 [N_REL]          4000
constexpr size_t OFF_U0    = 404000;                   // f64 [256]            2048
constexpr size_t OFF_EMB   = 406048;                   // f32 [N_ENT][256]  51200000
constexpr size_t OFF_NEIGH = OFF_EMB + 51200000;       // f32 [N_ENT][256]  51200000
constexpr size_t OFF_SS    = OFF_NEIGH + 51200000;     // f32 [N_ENT][8]     1600000
constexpr size_t OFF_RELT  = OFF_SS + 1600000;         // f32 [N_REL][256]    512000
constexpr size_t OFF_SR4   = OFF_RELT + 512000;        // f32 [N_REL][4]        8000
constexpr size_t OFF_U8    = OFF_SR4 + 8000;           // f32 [256][8]          8192
constexpr size_t WS_NEED   = OFF_U8 + 8192;            // ~105 MB

__device__ __forceinline__ float leaky(float x) { return x >= 0.f ? x : 0.2f * x; }

// ---------------- K1: U vectors ----------------
// U8[d][h]   = sum_e W[h][d][e]*a[h][e]       (src)
// U8[d][4+h] = sum_e W[h][d][e]*a[h][64+e]    (dst)
// u0[d]      = f64 sum_e W[0][d][e]*a[0][e]
__global__ void prep_kernel(const float* __restrict__ W, const float* __restrict__ a,
                            float* __restrict__ U8, double* __restrict__ u0)
{
    int d = threadIdx.x; // 256 threads, 1 block
    for (int h = 0; h < N_HEADS; ++h) {
        float ss = 0.f, sd = 0.f;
        for (int e = 0; e < HEAD_DIM; ++e) {
            float w = W[h * 16384 + d * 64 + e];
            ss += w * a[h * 192 + e];
            sd += w * a[h * 192 + 64 + e];
        }
        U8[d * 8 + h] = ss;
        U8[d * 8 + 4 + h] = sd;
    }
    double s0 = 0.0;
    for (int e = 0; e < HEAD_DIM; ++e)
        s0 += (double)W[d * 64 + e] * (double)a[e];
    u0[d] = s0;
}

// ---------------- K2: relation transform ----------------
// rel_t[r][h*64+e], sr4[r][h] = rel_t[h][r]·a3[h][2], sr0[r] = f64 head0 version
__global__ __launch_bounds__(64) void rel_kernel(
    const float* __restrict__ rel_emb, const float* __restrict__ W_r,
    const float* __restrict__ a,
    float* __restrict__ rel_t, float* __restrict__ sr4, double* __restrict__ sr0)
{
    int r = blockIdx.x;
    int l = threadIdx.x;
    int h = l >> 4;
    int e4 = (l & 15) << 2;
    const float* Wh = W_r + h * 16384 + e4;

    float ax = 0.f, ay = 0.f, az = 0.f, aw = 0.f;
    double dx = 0.0, dy = 0.0, dz = 0.0, dw = 0.0;
    #pragma unroll 4
    for (int d = 0; d < 256; ++d) {
        float x = rel_emb[r * 256 + d];
        float4 w = *(const float4*)(Wh + d * 64);
        ax += x * w.x; ay += x * w.y; az += x * w.z; aw += x * w.w;
        dx += (double)x * w.x; dy += (double)x * w.y;
        dz += (double)x * w.z; dw += (double)x * w.w;
    }
    float4 acc; acc.x = ax; acc.y = ay; acc.z = az; acc.w = aw;
    *(float4*)(rel_t + r * 256 + l * 4) = acc;

    // sr4: per-head dot with a[h*192+128+e]
    const float* ar = a + h * 192 + 128 + e4;
    float s = ax * ar[0] + ay * ar[1] + az * ar[2] + aw * ar[3];
    #pragma unroll
    for (int m = 1; m <= 8; m <<= 1) s += __shfl_xor(s, m);
    if ((l & 15) == 0) sr4[r * 4 + h] = s;

    // sr0 (f64, head 0 lanes only hold meaningful data)
    double sd = dx * (double)a[128 + e4] + dy * (double)a[128 + e4 + 1] +
                dz * (double)a[128 + e4 + 2] + dw * (double)a[128 + e4 + 3];
    #pragma unroll
    for (int m = 1; m <= 8; m <<= 1) sd += __shfl_xor(sd, m);
    if (l == 0) sr0[r] = sd;
}

// ---------------- K3: SS = E @ U8 (f32), ssrc0 = E @ u0 (f64) ----------------
__global__ __launch_bounds__(256) void ss_kernel(
    const float* __restrict__ ent, const float* __restrict__ U8,
    const double* __restrict__ u0,
    float* __restrict__ SS, double* __restrict__ ssrc0)
{
    __shared__ float Ut[8][256];
    __shared__ double u0s[256];
    for (int i = threadIdx.x; i < 2048; i += 256)
        Ut[i >> 8][i & 255] = U8[(i & 255) * 8 + (i >> 8)];
    for (int i = threadIdx.x; i < 256; i += 256) u0s[i] = u0[i];
    __syncthreads();

    int l = threadIdx.x & 63;
    int wave = (blockIdx.x * 256 + threadIdx.x) >> 6;
    int nwaves = gridDim.x * 4;
    for (int n = wave; n < N_ENT; n += nwaves) {
        float4 x = *(const float4*)(ent + (size_t)n * 256 + 4 * l);
        float p[8];
        #pragma unroll
        for (int j = 0; j < 8; ++j) {
            float4 u = *(const float4*)&Ut[j][4 * l];
            p[j] = x.x * u.x + x.y * u.y + x.z * u.z + x.w * u.w;
        }
        double pd = (double)x.x * u0s[4 * l] + (double)x.y * u0s[4 * l + 1] +
                    (double)x.z * u0s[4 * l + 2] + (double)x.w * u0s[4 * l + 3];
        #pragma unroll
        for (int off = 32; off > 0; off >>= 1) {
            #pragma unroll
            for (int j = 0; j < 8; ++j) p[j] += __shfl_xor(p[j], off);
            pd += __shfl_xor(pd, off);
        }
        if (l == 0) {
            float4 o1; o1.x = p[0]; o1.y = p[1]; o1.z = p[2]; o1.w = p[3];
            float4 o2; o2.x = p[4]; o2.y = p[5]; o2.z = p[6]; o2.w = p[7];
            *(float4*)(SS + (size_t)n * 8) = o1;
            *(float4*)(SS + (size_t)n * 8 + 4) = o2;
            ssrc0[n] = pd;
        }
    }
}

// ---------------- K4/K6: f32 SGEMM, C[M,256] = A[M,256] @ B' ----------------
// B'[k][c] for column tile by: Bb = B + by*head_stride, col = by*col_mul + c, ld = ldb
__global__ __launch_bounds__(256) void gemm_k(
    const float* __restrict__ A, const float* __restrict__ B,
    float* __restrict__ C, int M, int ldb, int head_stride, int col_mul, int do_tanh)
{
    __shared__ float As[64][68]; // [k][m] (transposed on store)
    __shared__ float Bs[64][68]; // [k][n]
    int by = blockIdx.y;
    int bm = blockIdx.x * 64;
    const float* Bb = B + (size_t)by * head_stride;
    int bcol = by * col_mul;
    int tid = threadIdx.x;
    int tx = tid & 15, ty = tid >> 4;
    float acc[4][4] = {};

    for (int k0 = 0; k0 < 256; k0 += 64) {
        #pragma unroll
        for (int i = 0; i < 4; ++i) {
            int idx = tid + i * 256;
            int r = idx >> 4;
            int c4 = (idx & 15) << 2;
            int row = bm + r;
            float4 v = make_float4(0.f, 0.f, 0.f, 0.f);
            if (row < M) v = *(const float4*)(A + (size_t)row * 256 + k0 + c4);
            As[c4 + 0][r] = v.x; As[c4 + 1][r] = v.y;
            As[c4 + 2][r] = v.z; As[c4 + 3][r] = v.w;
            float4 w = *(const float4*)(Bb + (size_t)(k0 + r) * ldb + bcol + c4);
            *(float4*)&Bs[r][c4] = w;
        }
        __syncthreads();
        #pragma unroll
        for (int kk = 0; kk < 64; ++kk) {
            float4 a4 = *(float4*)&As[kk][ty << 2];
            float4 b4 = *(float4*)&Bs[kk][tx << 2];
            float av[4] = {a4.x, a4.y, a4.z, a4.w};
            float bv[4] = {b4.x, b4.y, b4.z, b4.w};
            #pragma unroll
            for (int i2 = 0; i2 < 4; ++i2)
                #pragma unroll
                for (int j2 = 0; j2 < 4; ++j2) acc[i2][j2] += av[i2] * bv[j2];
        }
        __syncthreads();
    }

    int col0 = by * 64 + (tx << 2);
    #pragma unroll
    for (int i2 = 0; i2 < 4; ++i2) {
        int row = bm + (ty << 2) + i2;
        if (row < M) {
            float4 o;
            o.x = acc[i2][0]; o.y = acc[i2][1]; o.z = acc[i2][2]; o.w = acc[i2][3];
            if (do_tanh) {
                o.x = tanhf(o.x); o.y = tanhf(o.y); o.z = tanhf(o.z); o.w = tanhf(o.w);
            }
            *(float4*)(C + (size_t)row * 256 + col0) = o;
        }
    }
}

// ---------------- K5: per-node top-k + softmax + aggregate ----------------
// one wave per node, 4 nodes per block
__global__ __launch_bounds__(256) void node_kernel(
    const int* __restrict__ src, const int* __restrict__ relid,
    const float* __restrict__ SS, const double* __restrict__ ssrc0,
    const float* __restrict__ emb_t, const float* __restrict__ rel_t,
    const float* __restrict__ sr4, const double* __restrict__ sr0,
    float* __restrict__ neigh)
{
    __shared__ __align__(16) float sr4s[N_REL * 4];
    __shared__ double sr0s[N_REL];
    for (int i = threadIdx.x; i < N_REL; i += 256) {
        *(float4*)&sr4s[i * 4] = *(const float4*)&sr4[i * 4];
        sr0s[i] = sr0[i];
    }
    __syncthreads();

    int l = threadIdx.x & 63;
    int n = blockIdx.x * 4 + (threadIdx.x >> 6); // 12500*4 == 50000 exactly
    bool valid = l < DEG;

    int sd_ = valid ? src[n * DEG + l] : 0;
    int rd_ = valid ? relid[n * DEG + l] : 0;

    // selection score (f64): s_dst is constant per row, leaky is monotone -> drop both
    double sc0 = valid ? (ssrc0[sd_] + sr0s[rd_]) : -1e300;

    // rank by count (stable, lower index wins ties == jax.lax.top_k)
    int cnt = 0;
    #pragma unroll
    for (int j = 0; j < DEG; ++j) {
        double sj = __shfl(sc0, j);
        cnt += (sj > sc0 || (sj == sc0 && j < l)) ? 1 : 0;
    }
    bool sel = valid && (cnt < TOPK);
    unsigned long long mask = __ballot(sel);

    // all-head f32 scores for own edge
    float4 ssv = make_float4(0.f, 0.f, 0.f, 0.f);
    float4 srv = make_float4(0.f, 0.f, 0.f, 0.f);
    if (valid) {
        ssv = *(const float4*)(SS + (size_t)sd_ * 8);
        srv = *(const float4*)&sr4s[rd_ * 4];
    }
    float4 sdv = *(const float4*)(SS + (size_t)n * 8 + 4);
    float4 sc4;
    sc4.x = leaky(ssv.x + sdv.x + srv.x);
    sc4.y = leaky(ssv.y + sdv.y + srv.y);
    sc4.z = leaky(ssv.z + sdv.z + srv.z);
    sc4.w = leaky(ssv.w + sdv.w + srv.w);

    // pass 1: per-head max over selected
    float4 m4 = make_float4(-1e30f, -1e30f, -1e30f, -1e30f);
    unsigned long long mm = mask;
    #pragma unroll
    for (int k = 0; k < TOPK; ++k) {
        int lk = __builtin_ctzll(mm); mm &= mm - 1;
        m4.x = fmaxf(m4.x, __shfl(sc4.x, lk));
        m4.y = fmaxf(m4.y, __shfl(sc4.y, lk));
        m4.z = fmaxf(m4.z, __shfl(sc4.z, lk));
        m4.w = fmaxf(m4.w, __shfl(sc4.w, lk));
    }
    // pass 2: per-head sum of exp
    float4 s4 = make_float4(0.f, 0.f, 0.f, 0.f);
    mm = mask;
    #pragma unroll
    for (int k = 0; k < TOPK; ++k) {
        int lk = __builtin_ctzll(mm); mm &= mm - 1;
        s4.x += __expf(__shfl(sc4.x, lk) - m4.x);
        s4.y += __expf(__shfl(sc4.y, lk) - m4.y);
        s4.z += __expf(__shfl(sc4.z, lk) - m4.z);
        s4.w += __expf(__shfl(sc4.w, lk) - m4.w);
    }

    int h = l >> 4; // head owning this lane's 4 dims
    float mh = h == 0 ? m4.x : h == 1 ? m4.y : h == 2 ? m4.z : m4.w;
    float sh = h == 0 ? s4.x : h == 1 ? s4.y : h == 2 ? s4.z : s4.w;
    float rs = 1.f / sh;

    // pass 3: weighted aggregation of comp = emb_t[src_k] + rel_t[rel_k]
    float4 acc = make_float4(0.f, 0.f, 0.f, 0.f);
    mm = mask;
    #pragma unroll
    for (int k = 0; k < TOPK; ++k) {
        int lk = __builtin_ctzll(mm); mm &= mm - 1;
        int sk = __shfl(sd_, lk);
        int rk = __shfl(rd_, lk);
        float scx = __shfl(sc4.x, lk), scy = __shfl(sc4.y, lk);
        float scz = __shfl(sc4.z, lk), scw = __shfl(sc4.w, lk);
        float sch = h == 0 ? scx : h == 1 ? scy : h == 2 ? scz : scw;
        float w = __expf(sch - mh) * rs;
        float4 e4 = *(const float4*)(emb_t + (size_t)sk * 256 + 4 * l);
        float4 r4 = *(const float4*)(rel_t + (size_t)rk * 256 + 4 * l);
        acc.x += w * (e4.x + r4.x);
        acc.y += w * (e4.y + r4.y);
        acc.z += w * (e4.z + r4.z);
        acc.w += w * (e4.w + r4.w);
    }
    *(float4*)(neigh + (size_t)n * 256 + 4 * l) = acc;
}

extern "C" void kernel_launch(void* const* d_in, const int* in_sizes, int n_in,
                              void* d_out, int out_size, void* d_ws, size_t ws_size,
                              hipStream_t stream) {
    const float* ent  = (const float*)d_in[0];
    const float* rel  = (const float*)d_in[1];
    const float* W    = (const float*)d_in[2];
    const float* W_r  = (const float*)d_in[3];
    const float* a    = (const float*)d_in[4];
    const float* nw   = (const float*)d_in[5];
    const int*   srcp = (const int*)d_in[6];
    const int*   ridp = (const int*)d_in[7];
    float* out = (float*)d_out;

    if (ws_size < WS_NEED) return; // loud failure instead of corruption

    char* ws = (char*)d_ws;
    double* ssrc0 = (double*)(ws + OFF_SSRC0);
    double* sr0   = (double*)(ws + OFF_SR0);
    double* u0    = (double*)(ws + OFF_U0);
    float*  emb_t = (float*)(ws + OFF_EMB);
    float*  neigh = (float*)(ws + OFF_NEIGH);
    float*  SS    = (float*)(ws + OFF_SS);
    float*  rel_t = (float*)(ws + OFF_RELT);
    float*  sr4   = (float*)(ws + OFF_SR4);
    float*  U8    = (float*)(ws + OFF_U8);

    prep_kernel<<<1, 256, 0, stream>>>(W, a, U8, u0);
    rel_kernel<<<N_REL, 64, 0, stream>>>(rel, W_r, a, rel_t, sr4, sr0);
    ss_kernel<<<512, 256, 0, stream>>>(ent, U8, u0, SS, ssrc0);
    gemm_k<<<dim3(782, 4), 256, 0, stream>>>(ent, W, emb_t, N_ENT, 64, 16384, 0, 0);
    node_kernel<<<12500, 256, 0, stream>>>(srcp, ridp, SS, ssrc0, emb_t, rel_t, sr4, sr0, neigh);
    gemm_k<<<dim3(782, 4), 256, 0, stream>>>(neigh, nw, out, N_ENT, 256, 0, 64, 1);
}

// Round 2
// 305.325 us; speedup vs baseline: 1.3821x; 1.3821x over previous
//
#include <hip/hip_runtime.h>
#include <math.h>

#define N_ENT 50000
#define N_REL 500
#define DEG 32
#define TOPK 10
#define H_DIM 256
#define N_HEADS 4
#define HEAD_DIM 64

typedef __attribute__((ext_vector_type(8))) short short8v;
typedef __attribute__((ext_vector_type(4))) float f32x4;

// ---------------- workspace layout (bytes) ----------------
constexpr size_t OFF_SSRC0 = 0;                        // f64 [N_ENT]        400000
constexpr size_t OFF_SR0   = 400000;                   // f64 [N_REL]          4000
constexpr size_t OFF_U0    = 404000;                   // f64 [256]            2048
constexpr size_t OFF_EMB   = 406048;                   // f32 [N_ENT][256]  51200000
constexpr size_t OFF_NEIGH = OFF_EMB + 51200000;       // f32 [N_ENT][256]  51200000
constexpr size_t OFF_SS    = OFF_NEIGH + 51200000;     // f32 [N_ENT][8]     1600000
constexpr size_t OFF_RELT  = OFF_SS + 1600000;         // f32 [N_REL][256]    512000
constexpr size_t OFF_SR4   = OFF_RELT + 512000;        // f32 [N_REL][4]        8000
constexpr size_t OFF_U8    = OFF_SR4 + 8000;           // f32 [256][8]          8192
constexpr size_t OFF_B1H   = OFF_U8 + 8192;            // bf16 [256][256]     131072
constexpr size_t OFF_B1L   = OFF_B1H + 131072;
constexpr size_t OFF_B2H   = OFF_B1L + 131072;
constexpr size_t OFF_B2L   = OFF_B2H + 131072;
constexpr size_t WS_NEED   = OFF_B2L + 131072;         // ~106 MB

__device__ __forceinline__ float leaky(float x) { return x >= 0.f ? x : 0.2f * x; }

__device__ __forceinline__ unsigned short bf16_rne(float x) {
    unsigned int u = __float_as_uint(x);
    unsigned int r = u + 0x7fffu + ((u >> 16) & 1u);
    return (unsigned short)(r >> 16);
}

// ---------------- K1: U vectors ----------------
__global__ void prep_kernel(const float* __restrict__ W, const float* __restrict__ a,
                            float* __restrict__ U8, double* __restrict__ u0)
{
    int d = threadIdx.x; // 256 threads, 1 block
    for (int h = 0; h < N_HEADS; ++h) {
        float ss = 0.f, sd = 0.f;
        for (int e = 0; e < HEAD_DIM; ++e) {
            float w = W[h * 16384 + d * 64 + e];
            ss += w * a[h * 192 + e];
            sd += w * a[h * 192 + 64 + e];
        }
        U8[d * 8 + h] = ss;
        U8[d * 8 + 4 + h] = sd;
    }
    double s0 = 0.0;
    for (int e = 0; e < HEAD_DIM; ++e)
        s0 += (double)W[d * 64 + e] * (double)a[e];
    u0[d] = s0;
}

// ---------------- K1b: split B matrices to bf16 hi/lo, transposed [n][k] ----------------
// B1: Bt1[c][d] = W[h][d][e], c=h*64+e   (for emb_t = E @ Wcat)
// B2: Bt2[n][k] = nw[k][n]               (for out = neigh @ nw)
__global__ __launch_bounds__(256) void bsplit_kernel(
    const float* __restrict__ W, const float* __restrict__ nw,
    unsigned short* __restrict__ b1h, unsigned short* __restrict__ b1l,
    unsigned short* __restrict__ b2h, unsigned short* __restrict__ b2l)
{
    int n = blockIdx.x;    // 0..255 (output col)
    int k = threadIdx.x;   // 0..255 (inner dim)
    int h = n >> 6, e = n & 63;
    float x1 = W[h * 16384 + k * 64 + e];
    float x2 = nw[k * 256 + n];
    unsigned short h1 = bf16_rne(x1);
    float f1 = __uint_as_float((unsigned)h1 << 16);
    unsigned short l1 = bf16_rne(x1 - f1);
    unsigned short h2 = bf16_rne(x2);
    float f2 = __uint_as_float((unsigned)h2 << 16);
    unsigned short l2 = bf16_rne(x2 - f2);
    b1h[n * 256 + k] = h1; b1l[n * 256 + k] = l1;
    b2h[n * 256 + k] = h2; b2l[n * 256 + k] = l2;
}

// ---------------- K2: relation transform ----------------
__global__ __launch_bounds__(64) void rel_kernel(
    const float* __restrict__ rel_emb, const float* __restrict__ W_r,
    const float* __restrict__ a,
    float* __restrict__ rel_t, float* __restrict__ sr4, double* __restrict__ sr0)
{
    int r = blockIdx.x;
    int l = threadIdx.x;
    int h = l >> 4;
    int e4 = (l & 15) << 2;
    const float* Wh = W_r + h * 16384 + e4;

    float ax = 0.f, ay = 0.f, az = 0.f, aw = 0.f;
    double dx = 0.0, dy = 0.0, dz = 0.0, dw = 0.0;
    #pragma unroll 4
    for (int d = 0; d < 256; ++d) {
        float x = rel_emb[r * 256 + d];
        float4 w = *(const float4*)(Wh + d * 64);
        ax += x * w.x; ay += x * w.y; az += x * w.z; aw += x * w.w;
        dx += (double)x * w.x; dy += (double)x * w.y;
        dz += (double)x * w.z; dw += (double)x * w.w;
    }
    float4 acc; acc.x = ax; acc.y = ay; acc.z = az; acc.w = aw;
    *(float4*)(rel_t + r * 256 + l * 4) = acc;

    const float* ar = a + h * 192 + 128 + e4;
    float s = ax * ar[0] + ay * ar[1] + az * ar[2] + aw * ar[3];
    #pragma unroll
    for (int m = 1; m <= 8; m <<= 1) s += __shfl_xor(s, m);
    if ((l & 15) == 0) sr4[r * 4 + h] = s;

    double sd = dx * (double)a[128 + e4] + dy * (double)a[128 + e4 + 1] +
                dz * (double)a[128 + e4 + 2] + dw * (double)a[128 + e4 + 3];
    #pragma unroll
    for (int m = 1; m <= 8; m <<= 1) sd += __shfl_xor(sd, m);
    if (l == 0) sr0[r] = sd;
}

// ---------------- K3: SS = E @ U8 (f32), ssrc0 = E @ u0 (f64) ----------------
__global__ __launch_bounds__(256) void ss_kernel(
    const float* __restrict__ ent, const float* __restrict__ U8,
    const double* __restrict__ u0,
    float* __restrict__ SS, double* __restrict__ ssrc0)
{
    __shared__ float Ut[8][256];
    __shared__ double u0s[256];
    for (int i = threadIdx.x; i < 2048; i += 256)
        Ut[i >> 8][i & 255] = U8[(i & 255) * 8 + (i >> 8)];
    for (int i = threadIdx.x; i < 256; i += 256) u0s[i] = u0[i];
    __syncthreads();

    int l = threadIdx.x & 63;
    int wave = (blockIdx.x * 256 + threadIdx.x) >> 6;
    int nwaves = gridDim.x * 4;
    for (int n = wave; n < N_ENT; n += nwaves) {
        float4 x = *(const float4*)(ent + (size_t)n * 256 + 4 * l);
        float p[8];
        #pragma unroll
        for (int j = 0; j < 8; ++j) {
            float4 u = *(const float4*)&Ut[j][4 * l];
            p[j] = x.x * u.x + x.y * u.y + x.z * u.z + x.w * u.w;
        }
        double pd = (double)x.x * u0s[4 * l] + (double)x.y * u0s[4 * l + 1] +
                    (double)x.z * u0s[4 * l + 2] + (double)x.w * u0s[4 * l + 3];
        #pragma unroll
        for (int off = 32; off > 0; off >>= 1) {
            #pragma unroll
            for (int j = 0; j < 8; ++j) p[j] += __shfl_xor(p[j], off);
            pd += __shfl_xor(pd, off);
        }
        if (l == 0) {
            float4 o1; o1.x = p[0]; o1.y = p[1]; o1.z = p[2]; o1.w = p[3];
            float4 o2; o2.x = p[4]; o2.y = p[5]; o2.z = p[6]; o2.w = p[7];
            *(float4*)(SS + (size_t)n * 8) = o1;
            *(float4*)(SS + (size_t)n * 8 + 4) = o2;
            ssrc0[n] = pd;
        }
    }
}

// ---------------- K4/K6: split-bf16 MFMA GEMM ----------------
// C[M,256] = A[M,256] @ B[256,256], B pre-split/transposed: Bt[n][k] bf16 hi/lo.
// Block: 256 thr = 4 waves; block tile 64(M) x 256(N); wave tile 64x64.
// A staged to LDS as split bf16, double-buffered; B frags read straight from L2.
__global__ __launch_bounds__(256) void gemm_split(
    const float* __restrict__ A,
    const unsigned short* __restrict__ Bth,
    const unsigned short* __restrict__ Btl,
    float* __restrict__ C, int M, int do_tanh)
{
    __shared__ unsigned short AhS[2][64][40];  // padded pitch 40 -> 2-way banks only
    __shared__ unsigned short AlS[2][64][40];

    const int tid = threadIdx.x;
    const int l = tid & 63;
    const int w = tid >> 6;
    const int bm = blockIdx.x * 64;
    const int rl = l & 15;
    const int ql = l >> 4;

    // staging assignment: 64 rows x 32 k (8 float4/row); thread -> (row, q) twice
    const int srow = tid >> 3;     // 0..31
    const int sq   = tid & 7;
    const float* a0 = A + (size_t)(bm + srow) * 256 + sq * 4;
    const float* a1 = A + (size_t)(bm + srow + 32) * 256 + sq * 4;
    const bool g0 = (bm + srow) < M;
    const bool g1 = (bm + srow + 32) < M;

    const size_t boff = (size_t)(w * 64 + rl) * 256 + ql * 8;

    f32x4 acc[4][4];
    #pragma unroll
    for (int i = 0; i < 4; ++i)
        #pragma unroll
        for (int j = 0; j < 4; ++j) acc[i][j] = (f32x4){0.f, 0.f, 0.f, 0.f};

    // convert+store helper
    auto cvt_store = [&](f32x4 v, int row, int q, int buf) {
        unsigned short h[4], lo[4];
        #pragma unroll
        for (int j = 0; j < 4; ++j) {
            h[j] = bf16_rne(v[j]);
            float hf = __uint_as_float((unsigned)h[j] << 16);
            lo[j] = bf16_rne(v[j] - hf);
        }
        uint2 hp; hp.x = h[0] | ((unsigned)h[1] << 16); hp.y = h[2] | ((unsigned)h[3] << 16);
        uint2 lp; lp.x = lo[0] | ((unsigned)lo[1] << 16); lp.y = lo[2] | ((unsigned)lo[3] << 16);
        *(uint2*)&AhS[buf][row][q * 4] = hp;
        *(uint2*)&AlS[buf][row][q * 4] = lp;
    };

    // prologue: stage k-step 0 into buf 0
    {
        f32x4 v0 = g0 ? *(const f32x4*)(a0) : (f32x4){0.f, 0.f, 0.f, 0.f};
        f32x4 v1 = g1 ? *(const f32x4*)(a1) : (f32x4){0.f, 0.f, 0.f, 0.f};
        cvt_store(v0, srow, sq, 0);
        cvt_store(v1, srow + 32, sq, 0);
    }
    __syncthreads();

    int buf = 0;
    #pragma unroll
    for (int ks = 0; ks < 8; ++ks) {
        f32x4 v0, v1;
        const bool pf = ks < 7;
        if (pf) {
            v0 = g0 ? *(const f32x4*)(a0 + (ks + 1) * 32) : (f32x4){0.f, 0.f, 0.f, 0.f};
            v1 = g1 ? *(const f32x4*)(a1 + (ks + 1) * 32) : (f32x4){0.f, 0.f, 0.f, 0.f};
        }
        short8v bh[4], bl[4];
        #pragma unroll
        for (int nf = 0; nf < 4; ++nf) {
            bh[nf] = *(const short8v*)(Bth + boff + nf * 4096 + ks * 32);
            bl[nf] = *(const short8v*)(Btl + boff + nf * 4096 + ks * 32);
        }
        short8v ah[4], al[4];
        #pragma unroll
        for (int mf = 0; mf < 4; ++mf) {
            ah[mf] = *(const short8v*)&AhS[buf][mf * 16 + rl][ql * 8];
            al[mf] = *(const short8v*)&AlS[buf][mf * 16 + rl][ql * 8];
        }
        #pragma unroll
        for (int mf = 0; mf < 4; ++mf)
            #pragma unroll
            for (int nf = 0; nf < 4; ++nf) {
                acc[mf][nf] = __builtin_amdgcn_mfma_f32_16x16x32_bf16(ah[mf], bh[nf], acc[mf][nf], 0, 0, 0);
                acc[mf][nf] = __builtin_amdgcn_mfma_f32_16x16x32_bf16(ah[mf], bl[nf], acc[mf][nf], 0, 0, 0);
                acc[mf][nf] = __builtin_amdgcn_mfma_f32_16x16x32_bf16(al[mf], bh[nf], acc[mf][nf], 0, 0, 0);
            }
        if (pf) {
            cvt_store(v0, srow, sq, buf ^ 1);
            cvt_store(v1, srow + 32, sq, buf ^ 1);
        }
        __syncthreads();
        buf ^= 1;
    }

    // epilogue: D col = lane&15, row = (lane>>4)*4 + reg  (m89-verified)
    #pragma unroll
    for (int mf = 0; mf < 4; ++mf) {
        int row0 = bm + mf * 16 + ql * 4;
        #pragma unroll
        for (int nf = 0; nf < 4; ++nf) {
            int c = w * 64 + nf * 16 + rl;
            #pragma unroll
            for (int j = 0; j < 4; ++j) {
                int r = row0 + j;
                if (r < M) {
                    float v = acc[mf][nf][j];
                    if (do_tanh) v = tanhf(v);
                    C[(size_t)r * 256 + c] = v;
                }
            }
        }
    }
}

// ---------------- K5: per-node top-k + softmax + aggregate ----------------
__global__ __launch_bounds__(256) void node_kernel(
    const int* __restrict__ src, const int* __restrict__ relid,
    const float* __restrict__ SS, const double* __restrict__ ssrc0,
    const float* __restrict__ emb_t, const float* __restrict__ rel_t,
    const float* __restrict__ sr4, const double* __restrict__ sr0,
    float* __restrict__ neigh)
{
    __shared__ __align__(16) float sr4s[N_REL * 4];
    __shared__ double sr0s[N_REL];
    for (int i = threadIdx.x; i < N_REL; i += 256) {
        *(float4*)&sr4s[i * 4] = *(const float4*)&sr4[i * 4];
        sr0s[i] = sr0[i];
    }
    __syncthreads();

    int l = threadIdx.x & 63;
    int n = blockIdx.x * 4 + (threadIdx.x >> 6);
    bool valid = l < DEG;

    int sd_ = valid ? src[n * DEG + l] : 0;
    int rd_ = valid ? relid[n * DEG + l] : 0;

    double sc0 = valid ? (ssrc0[sd_] + sr0s[rd_]) : -1e300;

    int cnt = 0;
    #pragma unroll
    for (int j = 0; j < DEG; ++j) {
        double sj = __shfl(sc0, j);
        cnt += (sj > sc0 || (sj == sc0 && j < l)) ? 1 : 0;
    }
    bool sel = valid && (cnt < TOPK);
    unsigned long long mask = __ballot(sel);

    float4 ssv = make_float4(0.f, 0.f, 0.f, 0.f);
    float4 srv = make_float4(0.f, 0.f, 0.f, 0.f);
    if (valid) {
        ssv = *(const float4*)(SS + (size_t)sd_ * 8);
        srv = *(const float4*)&sr4s[rd_ * 4];
    }
    float4 sdv = *(const float4*)(SS + (size_t)n * 8 + 4);
    float4 sc4;
    sc4.x = leaky(ssv.x + sdv.x + srv.x);
    sc4.y = leaky(ssv.y + sdv.y + srv.y);
    sc4.z = leaky(ssv.z + sdv.z + srv.z);
    sc4.w = leaky(ssv.w + sdv.w + srv.w);

    float4 m4 = make_float4(-1e30f, -1e30f, -1e30f, -1e30f);
    unsigned long long mm = mask;
    #pragma unroll
    for (int k = 0; k < TOPK; ++k) {
        int lk = __builtin_ctzll(mm); mm &= mm - 1;
        m4.x = fmaxf(m4.x, __shfl(sc4.x, lk));
        m4.y = fmaxf(m4.y, __shfl(sc4.y, lk));
        m4.z = fmaxf(m4.z, __shfl(sc4.z, lk));
        m4.w = fmaxf(m4.w, __shfl(sc4.w, lk));
    }
    float4 s4 = make_float4(0.f, 0.f, 0.f, 0.f);
    mm = mask;
    #pragma unroll
    for (int k = 0; k < TOPK; ++k) {
        int lk = __builtin_ctzll(mm); mm &= mm - 1;
        s4.x += __expf(__shfl(sc4.x, lk) - m4.x);
        s4.y += __expf(__shfl(sc4.y, lk) - m4.y);
        s4.z += __expf(__shfl(sc4.z, lk) - m4.z);
        s4.w += __expf(__shfl(sc4.w, lk) - m4.w);
    }

    int h = l >> 4;
    float mh = h == 0 ? m4.x : h == 1 ? m4.y : h == 2 ? m4.z : m4.w;
    float sh = h == 0 ? s4.x : h == 1 ? s4.y : h == 2 ? s4.z : s4.w;
    float rs = 1.f / sh;

    float4 acc = make_float4(0.f, 0.f, 0.f, 0.f);
    mm = mask;
    #pragma unroll
    for (int k = 0; k < TOPK; ++k) {
        int lk = __builtin_ctzll(mm); mm &= mm - 1;
        int sk = __shfl(sd_, lk);
        int rk = __shfl(rd_, lk);
        float scx = __shfl(sc4.x, lk), scy = __shfl(sc4.y, lk);
        float scz = __shfl(sc4.z, lk), scw = __shfl(sc4.w, lk);
        float sch = h == 0 ? scx : h == 1 ? scy : h == 2 ? scz : scw;
        float wgt = __expf(sch - mh) * rs;
        float4 e4 = *(const float4*)(emb_t + (size_t)sk * 256 + 4 * l);
        float4 r4 = *(const float4*)(rel_t + (size_t)rk * 256 + 4 * l);
        acc.x += wgt * (e4.x + r4.x);
        acc.y += wgt * (e4.y + r4.y);
        acc.z += wgt * (e4.z + r4.z);
        acc.w += wgt * (e4.w + r4.w);
    }
    *(float4*)(neigh + (size_t)n * 256 + 4 * l) = acc;
}

extern "C" void kernel_launch(void* const* d_in, const int* in_sizes, int n_in,
                              void* d_out, int out_size, void* d_ws, size_t ws_size,
                              hipStream_t stream) {
    const float* ent  = (const float*)d_in[0];
    const float* rel  = (const float*)d_in[1];
    const float* W    = (const float*)d_in[2];
    const float* W_r  = (const float*)d_in[3];
    const float* a    = (const float*)d_in[4];
    const float* nw   = (const float*)d_in[5];
    const int*   srcp = (const int*)d_in[6];
    const int*   ridp = (const int*)d_in[7];
    float* out = (float*)d_out;

    if (ws_size < WS_NEED) return;

    char* ws = (char*)d_ws;
    double* ssrc0 = (double*)(ws + OFF_SSRC0);
    double* sr0   = (double*)(ws + OFF_SR0);
    double* u0    = (double*)(ws + OFF_U0);
    float*  emb_t = (float*)(ws + OFF_EMB);
    float*  neigh = (float*)(ws + OFF_NEIGH);
    float*  SS    = (float*)(ws + OFF_SS);
    float*  rel_t = (float*)(ws + OFF_RELT);
    float*  sr4   = (float*)(ws + OFF_SR4);
    float*  U8    = (float*)(ws + OFF_U8);
    unsigned short* b1h = (unsigned short*)(ws + OFF_B1H);
    unsigned short* b1l = (unsigned short*)(ws + OFF_B1L);
    unsigned short* b2h = (unsigned short*)(ws + OFF_B2H);
    unsigned short* b2l = (unsigned short*)(ws + OFF_B2L);

    prep_kernel<<<1, 256, 0, stream>>>(W, a, U8, u0);
    bsplit_kernel<<<256, 256, 0, stream>>>(W, nw, b1h, b1l, b2h, b2l);
    rel_kernel<<<N_REL, 64, 0, stream>>>(rel, W_r, a, rel_t, sr4, sr0);
    ss_kernel<<<512, 256, 0, stream>>>(ent, U8, u0, SS, ssrc0);
    gemm_split<<<782, 256, 0, stream>>>(ent, b1h, b1l, emb_t, N_ENT, 0);
    node_kernel<<<12500, 256, 0, stream>>>(srcp, ridp, SS, ssrc0, emb_t, rel_t, sr4, sr0, neigh);
    gemm_split<<<782, 256, 0, stream>>>(neigh, b2h, b2l, out, N_ENT, 1);
}

// Round 3
// 289.062 us; speedup vs baseline: 1.4598x; 1.0563x over previous
//
#include <hip/hip_runtime.h>
#include <math.h>

#define N_ENT 50000
#define N_REL 500
#define DEG 32
#define TOPK 10
#define H_DIM 256
#define N_HEADS 4
#define HEAD_DIM 64

typedef __attribute__((ext_vector_type(8))) short short8v;
typedef __attribute__((ext_vector_type(4))) float f32x4;

// ---------------- workspace layout (bytes) ----------------
constexpr size_t OFF_SSRC0 = 0;                      // f64 [N_ENT]
constexpr size_t OFF_SR0   = 400000;                 // f64 [N_REL]
constexpr size_t OFF_U0    = 404000;                 // f64 [256]
constexpr size_t OFF_SS    = 406048;                 // f32 [N_ENT][8]
constexpr size_t OFF_SR4   = 2006048;                // f32 [N_REL][4]
constexpr size_t OFF_U8    = 2014048;                // f32 [256][8]
constexpr size_t OFF_B1H   = 2022240;                // bf16 [256][256] x4
constexpr size_t OFF_B1L   = 2153312;
constexpr size_t OFF_B2H   = 2284384;
constexpr size_t OFF_B2L   = 2415456;
constexpr size_t OFF_EAH   = 2546560;                // bf16 [N_ENT][256] (ent hi; later neigh hi)
constexpr size_t OFF_EAL   = 28146560;               // bf16 [N_ENT][256] (ent lo; later neigh lo)
constexpr size_t OFF_EMBBF = 53746560;               // bf16 [N_ENT][256] emb_t table
constexpr size_t OFF_RELBF = 79346560;               // bf16 [N_REL][256]
constexpr size_t WS_NEED   = 79602560;               // ~76 MB

__device__ __forceinline__ float leaky(float x) { return x >= 0.f ? x : 0.2f * x; }

__device__ __forceinline__ unsigned short bf16_rne(float x) {
    unsigned int u = __float_as_uint(x);
    unsigned int r = u + 0x7fffu + ((u >> 16) & 1u);
    return (unsigned short)(r >> 16);
}
__device__ __forceinline__ float bf2f(unsigned short x) {
    return __uint_as_float((unsigned)x << 16);
}

// ---------------- K1: U vectors ----------------
__global__ void prep_kernel(const float* __restrict__ W, const float* __restrict__ a,
                            float* __restrict__ U8, double* __restrict__ u0)
{
    int d = threadIdx.x; // 256 threads, 1 block
    for (int h = 0; h < N_HEADS; ++h) {
        float ss = 0.f, sd = 0.f;
        for (int e = 0; e < HEAD_DIM; ++e) {
            float w = W[h * 16384 + d * 64 + e];
            ss += w * a[h * 192 + e];
            sd += w * a[h * 192 + 64 + e];
        }
        U8[d * 8 + h] = ss;
        U8[d * 8 + 4 + h] = sd;
    }
    double s0 = 0.0;
    for (int e = 0; e < HEAD_DIM; ++e)
        s0 += (double)W[d * 64 + e] * (double)a[e];
    u0[d] = s0;
}

// ---------------- K1b: split B matrices to bf16 hi/lo, transposed [n][k] ----------------
__global__ __launch_bounds__(256) void bsplit_kernel(
    const float* __restrict__ W, const float* __restrict__ nw,
    unsigned short* __restrict__ b1h, unsigned short* __restrict__ b1l,
    unsigned short* __restrict__ b2h, unsigned short* __restrict__ b2l)
{
    int n = blockIdx.x;    // output col
    int k = threadIdx.x;   // inner dim
    int h = n >> 6, e = n & 63;
    float x1 = W[h * 16384 + k * 64 + e];
    float x2 = nw[k * 256 + n];
    unsigned short h1 = bf16_rne(x1);
    unsigned short l1 = bf16_rne(x1 - bf2f(h1));
    unsigned short h2 = bf16_rne(x2);
    unsigned short l2 = bf16_rne(x2 - bf2f(h2));
    b1h[n * 256 + k] = h1; b1l[n * 256 + k] = l1;
    b2h[n * 256 + k] = h2; b2l[n * 256 + k] = l2;
}

// ---------------- K2: relation transform (bf16 table + score pieces) ----------------
__global__ __launch_bounds__(64) void rel_kernel(
    const float* __restrict__ rel_emb, const float* __restrict__ W_r,
    const float* __restrict__ a,
    unsigned short* __restrict__ rel_bf, float* __restrict__ sr4, double* __restrict__ sr0)
{
    int r = blockIdx.x;
    int l = threadIdx.x;
    int h = l >> 4;
    int e4 = (l & 15) << 2;
    const float* Wh = W_r + h * 16384 + e4;

    float ax = 0.f, ay = 0.f, az = 0.f, aw = 0.f;
    double dx = 0.0, dy = 0.0, dz = 0.0, dw = 0.0;
    #pragma unroll 4
    for (int d = 0; d < 256; ++d) {
        float x = rel_emb[r * 256 + d];
        float4 w = *(const float4*)(Wh + d * 64);
        ax += x * w.x; ay += x * w.y; az += x * w.z; aw += x * w.w;
        dx += (double)x * w.x; dy += (double)x * w.y;
        dz += (double)x * w.z; dw += (double)x * w.w;
    }
    uint2 hp;
    hp.x = (unsigned)bf16_rne(ax) | ((unsigned)bf16_rne(ay) << 16);
    hp.y = (unsigned)bf16_rne(az) | ((unsigned)bf16_rne(aw) << 16);
    *(uint2*)(rel_bf + r * 256 + l * 4) = hp;

    const float* ar = a + h * 192 + 128 + e4;
    float s = ax * ar[0] + ay * ar[1] + az * ar[2] + aw * ar[3];
    #pragma unroll
    for (int m = 1; m <= 8; m <<= 1) s += __shfl_xor(s, m);
    if ((l & 15) == 0) sr4[r * 4 + h] = s;

    double sd = dx * (double)a[128 + e4] + dy * (double)a[128 + e4 + 1] +
                dz * (double)a[128 + e4 + 2] + dw * (double)a[128 + e4 + 3];
    #pragma unroll
    for (int m = 1; m <= 8; m <<= 1) sd += __shfl_xor(sd, m);
    if (l == 0) sr0[r] = sd;
}

// ---------------- K3: SS = E @ U8 (f32), ssrc0 = E @ u0 (f64), + split ent to bf16 hi/lo ----------------
__global__ __launch_bounds__(256) void ss_kernel(
    const float* __restrict__ ent, const float* __restrict__ U8,
    const double* __restrict__ u0,
    float* __restrict__ SS, double* __restrict__ ssrc0,
    unsigned short* __restrict__ eah, unsigned short* __restrict__ eal)
{
    __shared__ float Ut[8][256];
    __shared__ double u0s[256];
    for (int i = threadIdx.x; i < 2048; i += 256)
        Ut[i >> 8][i & 255] = U8[(i & 255) * 8 + (i >> 8)];
    for (int i = threadIdx.x; i < 256; i += 256) u0s[i] = u0[i];
    __syncthreads();

    int l = threadIdx.x & 63;
    int wave = (blockIdx.x * 256 + threadIdx.x) >> 6;
    int nwaves = gridDim.x * 4;
    for (int n = wave; n < N_ENT; n += nwaves) {
        float4 x = *(const float4*)(ent + (size_t)n * 256 + 4 * l);

        // split write
        unsigned short h0 = bf16_rne(x.x), h1 = bf16_rne(x.y),
                       h2 = bf16_rne(x.z), h3 = bf16_rne(x.w);
        uint2 hp; hp.x = (unsigned)h0 | ((unsigned)h1 << 16);
        hp.y = (unsigned)h2 | ((unsigned)h3 << 16);
        uint2 lp;
        lp.x = (unsigned)bf16_rne(x.x - bf2f(h0)) | ((unsigned)bf16_rne(x.y - bf2f(h1)) << 16);
        lp.y = (unsigned)bf16_rne(x.z - bf2f(h2)) | ((unsigned)bf16_rne(x.w - bf2f(h3)) << 16);
        *(uint2*)(eah + (size_t)n * 256 + 4 * l) = hp;
        *(uint2*)(eal + (size_t)n * 256 + 4 * l) = lp;

        float p[8];
        #pragma unroll
        for (int j = 0; j < 8; ++j) {
            float4 u = *(const float4*)&Ut[j][4 * l];
            p[j] = x.x * u.x + x.y * u.y + x.z * u.z + x.w * u.w;
        }
        double pd = (double)x.x * u0s[4 * l] + (double)x.y * u0s[4 * l + 1] +
                    (double)x.z * u0s[4 * l + 2] + (double)x.w * u0s[4 * l + 3];
        #pragma unroll
        for (int off = 32; off > 0; off >>= 1) {
            #pragma unroll
            for (int j = 0; j < 8; ++j) p[j] += __shfl_xor(p[j], off);
            pd += __shfl_xor(pd, off);
        }
        if (l == 0) {
            float4 o1; o1.x = p[0]; o1.y = p[1]; o1.z = p[2]; o1.w = p[3];
            float4 o2; o2.x = p[4]; o2.y = p[5]; o2.z = p[6]; o2.w = p[7];
            *(float4*)(SS + (size_t)n * 8) = o1;
            *(float4*)(SS + (size_t)n * 8 + 4) = o2;
            ssrc0[n] = pd;
        }
    }
}

// ---------------- K4/K6: pre-split bf16 MFMA GEMM ----------------
// C[M,256] = (Ah+Al)[M,256] @ (Bh+Bl)[256,256]; B transposed [n][k].
// mode: 0 = f32 out, 1 = bf16 out, 2 = f32 + tanh
__global__ __launch_bounds__(256) void gemm_bs(
    const unsigned short* __restrict__ Ah, const unsigned short* __restrict__ Al,
    const unsigned short* __restrict__ Bth, const unsigned short* __restrict__ Btl,
    void* __restrict__ Cout, int M, int mode)
{
    __shared__ unsigned short AhS[2][64][40];  // padded pitch -> <=2-way banks
    __shared__ unsigned short AlS[2][64][40];

    const int tid = threadIdx.x;
    const int l = tid & 63;
    const int w = tid >> 6;
    const int bm = blockIdx.x * 64;
    const int rl = l & 15;
    const int ql = l >> 4;

    // staging: thread -> row tid>>2 (0..63), k-group (tid&3)*8
    const int srow = tid >> 2;
    const int sk0 = (tid & 3) << 3;
    const int grow = min(bm + srow, M - 1);
    const size_t abase = (size_t)grow * 256 + sk0;

    const size_t boff = (size_t)(w * 64 + rl) * 256 + ql * 8;

    f32x4 acc[4][4];
    #pragma unroll
    for (int i = 0; i < 4; ++i)
        #pragma unroll
        for (int j = 0; j < 4; ++j) acc[i][j] = (f32x4){0.f, 0.f, 0.f, 0.f};

    // prologue
    {
        short8v vh = *(const short8v*)(Ah + abase);
        short8v vl = *(const short8v*)(Al + abase);
        *(short8v*)&AhS[0][srow][sk0] = vh;
        *(short8v*)&AlS[0][srow][sk0] = vl;
    }
    __syncthreads();

    int buf = 0;
    #pragma unroll
    for (int ks = 0; ks < 8; ++ks) {
        short8v vh, vl;
        const bool pf = ks < 7;
        if (pf) {
            vh = *(const short8v*)(Ah + abase + (ks + 1) * 32);
            vl = *(const short8v*)(Al + abase + (ks + 1) * 32);
        }
        short8v bh[4], bl[4];
        #pragma unroll
        for (int nf = 0; nf < 4; ++nf) {
            bh[nf] = *(const short8v*)(Bth + boff + nf * 4096 + ks * 32);
            bl[nf] = *(const short8v*)(Btl + boff + nf * 4096 + ks * 32);
        }
        short8v ah[4], al[4];
        #pragma unroll
        for (int mf = 0; mf < 4; ++mf) {
            ah[mf] = *(const short8v*)&AhS[buf][mf * 16 + rl][ql * 8];
            al[mf] = *(const short8v*)&AlS[buf][mf * 16 + rl][ql * 8];
        }
        #pragma unroll
        for (int mf = 0; mf < 4; ++mf)
            #pragma unroll
            for (int nf = 0; nf < 4; ++nf) {
                acc[mf][nf] = __builtin_amdgcn_mfma_f32_16x16x32_bf16(ah[mf], bh[nf], acc[mf][nf], 0, 0, 0);
                acc[mf][nf] = __builtin_amdgcn_mfma_f32_16x16x32_bf16(ah[mf], bl[nf], acc[mf][nf], 0, 0, 0);
                acc[mf][nf] = __builtin_amdgcn_mfma_f32_16x16x32_bf16(al[mf], bh[nf], acc[mf][nf], 0, 0, 0);
            }
        if (pf) {
            *(short8v*)&AhS[buf ^ 1][srow][sk0] = vh;
            *(short8v*)&AlS[buf ^ 1][srow][sk0] = vl;
        }
        __syncthreads();
        buf ^= 1;
    }

    // epilogue: D col = lane&15, row = (lane>>4)*4 + reg
    #pragma unroll
    for (int mf = 0; mf < 4; ++mf) {
        int row0 = bm + mf * 16 + ql * 4;
        #pragma unroll
        for (int nf = 0; nf < 4; ++nf) {
            int c = w * 64 + nf * 16 + rl;
            #pragma unroll
            for (int j = 0; j < 4; ++j) {
                int r = row0 + j;
                if (r < M) {
                    float v = acc[mf][nf][j];
                    if (mode == 2) v = tanhf(v);
                    if (mode == 1)
                        ((unsigned short*)Cout)[(size_t)r * 256 + c] = bf16_rne(v);
                    else
                        ((float*)Cout)[(size_t)r * 256 + c] = v;
                }
            }
        }
    }
}

// ---------------- K5: per-node top-k + softmax + aggregate ----------------
// one wave per node; lanes 0..31 = edge slots for scoring; all 64 lanes = 2 edges x 8 dims for aggregation
__global__ __launch_bounds__(256) void node_kernel(
    const int* __restrict__ src, const int* __restrict__ relid,
    const float* __restrict__ SS, const double* __restrict__ ssrc0,
    const unsigned short* __restrict__ emb_bf, const unsigned short* __restrict__ rel_bf,
    const float* __restrict__ sr4, const double* __restrict__ sr0,
    unsigned short* __restrict__ nah, unsigned short* __restrict__ nal)
{
    __shared__ __align__(16) float sr4s[N_REL * 4];
    __shared__ double sr0s[N_REL];
    __shared__ float wls[4][32][4];   // unnormalized exp weights per node-in-block
    for (int i = threadIdx.x; i < N_REL; i += 256) {
        *(float4*)&sr4s[i * 4] = *(const float4*)&sr4[i * 4];
        sr0s[i] = sr0[i];
    }
    __syncthreads();

    const int tid = threadIdx.x;
    const int l = tid & 63;
    const int nw_ = tid >> 6;
    const int n = blockIdx.x * 4 + nw_;
    const int el = l & 31;
    const int q = l >> 5;
    const bool isedge = (l < 32);

    int sd_ = 0, rd_ = 0;
    double sc0 = -1e300;
    if (isedge) {
        sd_ = src[n * DEG + el];
        rd_ = relid[n * DEG + el];
        sc0 = ssrc0[sd_] + sr0s[rd_];
    }

    // rank by count among 32 candidates (stable: lower index wins ties)
    int cnt = 0;
    #pragma unroll
    for (int j = 0; j < DEG; ++j) {
        double sj = __shfl(sc0, j);
        cnt += (sj > sc0 || (sj == sc0 && j < el)) ? 1 : 0;
    }
    const bool sel = isedge && (cnt < TOPK);
    const unsigned mask = (unsigned)__ballot(sel);

    // f32 scores for selected edges only
    float scx = -1e30f, scy = -1e30f, scz = -1e30f, scw = -1e30f;
    if (sel) {
        float4 ssv = *(const float4*)(SS + (size_t)sd_ * 8);
        float4 srv = *(const float4*)&sr4s[rd_ * 4];
        float4 sdv = *(const float4*)(SS + (size_t)n * 8 + 4);
        scx = leaky(ssv.x + sdv.x + srv.x);
        scy = leaky(ssv.y + sdv.y + srv.y);
        scz = leaky(ssv.z + sdv.z + srv.z);
        scw = leaky(ssv.w + sdv.w + srv.w);
    }

    // butterfly max over the wave (unselected = -1e30)
    float mx = scx, my = scy, mz = scz, mw = scw;
    #pragma unroll
    for (int off = 1; off < 64; off <<= 1) {
        mx = fmaxf(mx, __shfl_xor(mx, off));
        my = fmaxf(my, __shfl_xor(my, off));
        mz = fmaxf(mz, __shfl_xor(mz, off));
        mw = fmaxf(mw, __shfl_xor(mw, off));
    }
    // exp on selected lanes, butterfly sum
    float ex = sel ? __expf(scx - mx) : 0.f;
    float ey = sel ? __expf(scy - my) : 0.f;
    float ez = sel ? __expf(scz - mz) : 0.f;
    float ew = sel ? __expf(scw - mw) : 0.f;
    float sx = ex, sy = ey, sz = ez, sw = ew;
    #pragma unroll
    for (int off = 1; off < 64; off <<= 1) {
        sx += __shfl_xor(sx, off);
        sy += __shfl_xor(sy, off);
        sz += __shfl_xor(sz, off);
        sw += __shfl_xor(sw, off);
    }

    if (sel) {
        float4 wv; wv.x = ex; wv.y = ey; wv.z = ez; wv.w = ew;
        *(float4*)&wls[nw_][el][0] = wv;
    }
    __syncthreads();

    // aggregation: this lane covers dims el*8 .. el*8+7 (head h), edge set parity q
    const int h = el >> 3;
    const float sh = h == 0 ? sx : h == 1 ? sy : h == 2 ? sz : sw;
    const float rsh = 1.f / sh;

    unsigned mm = mask;
    if (q) mm &= mm - 1;  // odd half starts at 2nd selected edge

    float acc[8] = {0.f, 0.f, 0.f, 0.f, 0.f, 0.f, 0.f, 0.f};
    #pragma unroll
    for (int t = 0; t < 5; ++t) {
        int lk = __builtin_ctz(mm);
        mm &= mm - 1; mm &= mm - 1;
        int sk = __shfl(sd_, lk);
        int rk = __shfl(rd_, lk);
        float wgt = wls[nw_][lk][h];
        short8v ev = *(const short8v*)(emb_bf + (size_t)sk * 256 + el * 8);
        short8v rv = *(const short8v*)(rel_bf + (size_t)rk * 256 + el * 8);
        #pragma unroll
        for (int j = 0; j < 8; ++j) {
            float e = bf2f((unsigned short)ev[j]);
            float r = bf2f((unsigned short)rv[j]);
            acc[j] += wgt * (e + r);
        }
    }
    // combine halves (even edges + odd edges)
    #pragma unroll
    for (int j = 0; j < 8; ++j) {
        acc[j] += __shfl_xor(acc[j], 32);
        acc[j] *= rsh;
    }

    // split-write this lane's 4 dims: dim base el*8 + q*4
    unsigned short hh[4], ll2[4];
    #pragma unroll
    for (int j = 0; j < 4; ++j) {
        float v = acc[q * 4 + j];
        hh[j] = bf16_rne(v);
        ll2[j] = bf16_rne(v - bf2f(hh[j]));
    }
    uint2 hp; hp.x = (unsigned)hh[0] | ((unsigned)hh[1] << 16);
    hp.y = (unsigned)hh[2] | ((unsigned)hh[3] << 16);
    uint2 lp; lp.x = (unsigned)ll2[0] | ((unsigned)ll2[1] << 16);
    lp.y = (unsigned)ll2[2] | ((unsigned)ll2[3] << 16);
    size_t o = (size_t)n * 256 + el * 8 + q * 4;
    *(uint2*)(nah + o) = hp;
    *(uint2*)(nal + o) = lp;
}

extern "C" void kernel_launch(void* const* d_in, const int* in_sizes, int n_in,
                              void* d_out, int out_size, void* d_ws, size_t ws_size,
                              hipStream_t stream) {
    const float* ent  = (const float*)d_in[0];
    const float* rel  = (const float*)d_in[1];
    const float* W    = (const float*)d_in[2];
    const float* W_r  = (const float*)d_in[3];
    const float* a    = (const float*)d_in[4];
    const float* nw   = (const float*)d_in[5];
    const int*   srcp = (const int*)d_in[6];
    const int*   ridp = (const int*)d_in[7];
    float* out = (float*)d_out;

    if (ws_size < WS_NEED) return;

    char* ws = (char*)d_ws;
    double* ssrc0 = (double*)(ws + OFF_SSRC0);
    double* sr0   = (double*)(ws + OFF_SR0);
    double* u0    = (double*)(ws + OFF_U0);
    float*  SS    = (float*)(ws + OFF_SS);
    float*  sr4   = (float*)(ws + OFF_SR4);
    float*  U8    = (float*)(ws + OFF_U8);
    unsigned short* b1h = (unsigned short*)(ws + OFF_B1H);
    unsigned short* b1l = (unsigned short*)(ws + OFF_B1L);
    unsigned short* b2h = (unsigned short*)(ws + OFF_B2H);
    unsigned short* b2l = (unsigned short*)(ws + OFF_B2L);
    unsigned short* eah = (unsigned short*)(ws + OFF_EAH);
    unsigned short* eal = (unsigned short*)(ws + OFF_EAL);
    unsigned short* embbf = (unsigned short*)(ws + OFF_EMBBF);
    unsigned short* relbf = (unsigned short*)(ws + OFF_RELBF);
    // neigh hi/lo alias the ent hi/lo region (ent split dead after gemm1)
    unsigned short* nah = eah;
    unsigned short* nal = eal;

    prep_kernel<<<1, 256, 0, stream>>>(W, a, U8, u0);
    bsplit_kernel<<<256, 256, 0, stream>>>(W, nw, b1h, b1l, b2h, b2l);
    rel_kernel<<<N_REL, 64, 0, stream>>>(rel, W_r, a, relbf, sr4, sr0);
    ss_kernel<<<512, 256, 0, stream>>>(ent, U8, u0, SS, ssrc0, eah, eal);
    gemm_bs<<<782, 256, 0, stream>>>(eah, eal, b1h, b1l, embbf, N_ENT, 1);
    node_kernel<<<12500, 256, 0, stream>>>(srcp, ridp, SS, ssrc0, embbf, relbf, sr4, sr0, nah, nal);
    gemm_bs<<<782, 256, 0, stream>>>(nah, nal, b2h, b2l, out, N_ENT, 2);
}

// Round 4
// 235.130 us; speedup vs baseline: 1.7947x; 1.2294x over previous
//
#include <hip/hip_runtime.h>
#include <math.h>

#define N_ENT 50000
#define N_REL 500
#define DEG 32
#define TOPK 10
#define H_DIM 256
#define N_HEADS 4
#define HEAD_DIM 64

typedef __attribute__((ext_vector_type(8))) short short8v;
typedef __attribute__((ext_vector_type(4))) float f32x4;

// ---------------- workspace layout (bytes) ----------------
constexpr size_t OFF_SSRC0 = 0;                      // f64 [N_ENT]
constexpr size_t OFF_SR0   = 400000;                 // f64 [N_REL]
constexpr size_t OFF_U0    = 404000;                 // f64 [256]
constexpr size_t OFF_SS    = 406048;                 // f32 [N_ENT][8]
constexpr size_t OFF_SR4   = 2006048;                // f32 [N_REL][4]
constexpr size_t OFF_U8    = 2014048;                // f32 [256][8]
constexpr size_t OFF_B1H   = 2022240;                // bf16 [256][256] x4
constexpr size_t OFF_B1L   = 2153312;
constexpr size_t OFF_B2H   = 2284384;
constexpr size_t OFF_B2L   = 2415456;
constexpr size_t OFF_EAH   = 2546560;                // bf16 [N_ENT][256] (ent hi; later neigh hi)
constexpr size_t OFF_EMBBF = 28146560;               // bf16 [N_ENT][256] emb_t table
constexpr size_t OFF_RELBF = 53746560;               // bf16 [N_REL][256]
constexpr size_t WS_NEED   = 54002560;               // ~52 MB

__device__ __forceinline__ float leaky(float x) { return x >= 0.f ? x : 0.2f * x; }

__device__ __forceinline__ unsigned short bf16_rne(float x) {
    unsigned int u = __float_as_uint(x);
    unsigned int r = u + 0x7fffu + ((u >> 16) & 1u);
    return (unsigned short)(r >> 16);
}
__device__ __forceinline__ float bf2f(unsigned short x) {
    return __uint_as_float((unsigned)x << 16);
}

// ---------------- K0: fused setup (rel transform | U vectors | B splits) ----------------
__global__ __launch_bounds__(256) void setup_kernel(
    const float* __restrict__ rel_emb, const float* __restrict__ W_r,
    const float* __restrict__ W, const float* __restrict__ a, const float* __restrict__ nw,
    unsigned short* __restrict__ rel_bf, float* __restrict__ sr4, double* __restrict__ sr0,
    float* __restrict__ U8, double* __restrict__ u0,
    unsigned short* __restrict__ b1h, unsigned short* __restrict__ b1l,
    unsigned short* __restrict__ b2h, unsigned short* __restrict__ b2l)
{
    const int bid = blockIdx.x;
    const int tid = threadIdx.x;
    if (bid < 125) {
        // relation transform: 4 relations per block
        int r = bid * 4 + (tid >> 6);
        int l = tid & 63;
        int h = l >> 4;
        int e4 = (l & 15) << 2;
        const float* Wh = W_r + h * 16384 + e4;

        float ax = 0.f, ay = 0.f, az = 0.f, aw = 0.f;
        double dx = 0.0, dy = 0.0, dz = 0.0, dw = 0.0;
        #pragma unroll 4
        for (int d = 0; d < 256; ++d) {
            float x = rel_emb[r * 256 + d];
            float4 w = *(const float4*)(Wh + d * 64);
            ax += x * w.x; ay += x * w.y; az += x * w.z; aw += x * w.w;
            dx += (double)x * w.x; dy += (double)x * w.y;
            dz += (double)x * w.z; dw += (double)x * w.w;
        }
        uint2 hp;
        hp.x = (unsigned)bf16_rne(ax) | ((unsigned)bf16_rne(ay) << 16);
        hp.y = (unsigned)bf16_rne(az) | ((unsigned)bf16_rne(aw) << 16);
        *(uint2*)(rel_bf + r * 256 + l * 4) = hp;

        const float* ar = a + h * 192 + 128 + e4;
        float s = ax * ar[0] + ay * ar[1] + az * ar[2] + aw * ar[3];
        #pragma unroll
        for (int m = 1; m <= 8; m <<= 1) s += __shfl_xor(s, m);
        if ((l & 15) == 0) sr4[r * 4 + h] = s;

        double sd = dx * (double)a[128 + e4] + dy * (double)a[128 + e4 + 1] +
                    dz * (double)a[128 + e4 + 2] + dw * (double)a[128 + e4 + 3];
        #pragma unroll
        for (int m = 1; m <= 8; m <<= 1) sd += __shfl_xor(sd, m);
        if (l == 0) sr0[r] = sd;
    } else if (bid == 125) {
        // U vectors
        int d = tid;
        for (int h = 0; h < N_HEADS; ++h) {
            float ss = 0.f, sd = 0.f;
            for (int e = 0; e < HEAD_DIM; ++e) {
                float w = W[h * 16384 + d * 64 + e];
                ss += w * a[h * 192 + e];
                sd += w * a[h * 192 + 64 + e];
            }
            U8[d * 8 + h] = ss;
            U8[d * 8 + 4 + h] = sd;
        }
        double s0 = 0.0;
        for (int e = 0; e < HEAD_DIM; ++e)
            s0 += (double)W[d * 64 + e] * (double)a[e];
        u0[d] = s0;
    } else {
        // B splits, transposed [n][k]
        int n = bid - 126;   // output col
        int k = tid;         // inner dim
        int h = n >> 6, e = n & 63;
        float x1 = W[h * 16384 + k * 64 + e];
        float x2 = nw[k * 256 + n];
        unsigned short h1 = bf16_rne(x1);
        unsigned short l1 = bf16_rne(x1 - bf2f(h1));
        unsigned short h2 = bf16_rne(x2);
        unsigned short l2 = bf16_rne(x2 - bf2f(h2));
        b1h[n * 256 + k] = h1; b1l[n * 256 + k] = l1;
        b2h[n * 256 + k] = h2; b2l[n * 256 + k] = l2;
    }
}

// ---------------- K3: SS = E @ U8 (f32), ssrc0 = E @ u0 (f64), + bf16-hi ent ----------------
__global__ __launch_bounds__(256) void ss_kernel(
    const float* __restrict__ ent, const float* __restrict__ U8,
    const double* __restrict__ u0,
    float* __restrict__ SS, double* __restrict__ ssrc0,
    unsigned short* __restrict__ eah)
{
    __shared__ float Ut[8][256];
    __shared__ double u0s[256];
    for (int i = threadIdx.x; i < 2048; i += 256)
        Ut[i >> 8][i & 255] = U8[(i & 255) * 8 + (i >> 8)];
    for (int i = threadIdx.x; i < 256; i += 256) u0s[i] = u0[i];
    __syncthreads();

    int l = threadIdx.x & 63;
    int wave = (blockIdx.x * 256 + threadIdx.x) >> 6;
    int nwaves = gridDim.x * 4;
    for (int n = wave; n < N_ENT; n += nwaves) {
        float4 x = *(const float4*)(ent + (size_t)n * 256 + 4 * l);

        uint2 hp;
        hp.x = (unsigned)bf16_rne(x.x) | ((unsigned)bf16_rne(x.y) << 16);
        hp.y = (unsigned)bf16_rne(x.z) | ((unsigned)bf16_rne(x.w) << 16);
        *(uint2*)(eah + (size_t)n * 256 + 4 * l) = hp;

        float p[8];
        #pragma unroll
        for (int j = 0; j < 8; ++j) {
            float4 u = *(const float4*)&Ut[j][4 * l];
            p[j] = x.x * u.x + x.y * u.y + x.z * u.z + x.w * u.w;
        }
        double pd = (double)x.x * u0s[4 * l] + (double)x.y * u0s[4 * l + 1] +
                    (double)x.z * u0s[4 * l + 2] + (double)x.w * u0s[4 * l + 3];
        #pragma unroll
        for (int off = 32; off > 0; off >>= 1) {
            #pragma unroll
            for (int j = 0; j < 8; ++j) p[j] += __shfl_xor(p[j], off);
            pd += __shfl_xor(pd, off);
        }
        if (l == 0) {
            float4 o1; o1.x = p[0]; o1.y = p[1]; o1.z = p[2]; o1.w = p[3];
            float4 o2; o2.x = p[4]; o2.y = p[5]; o2.z = p[6]; o2.w = p[7];
            *(float4*)(SS + (size_t)n * 8) = o1;
            *(float4*)(SS + (size_t)n * 8 + 4) = o2;
            ssrc0[n] = pd;
        }
    }
}

// ---------------- K4/K6: bf16 MFMA GEMM, C = Ah @ (Bh+Bl) ----------------
// mode: 1 = bf16 out, 2 = f32 + tanh
__global__ __launch_bounds__(256) void gemm_bs(
    const unsigned short* __restrict__ Ah,
    const unsigned short* __restrict__ Bth, const unsigned short* __restrict__ Btl,
    void* __restrict__ Cout, int M, int mode)
{
    __shared__ unsigned short AhS[2][64][40];  // padded pitch -> <=2-way banks

    const int tid = threadIdx.x;
    const int l = tid & 63;
    const int w = tid >> 6;
    const int bm = blockIdx.x * 64;
    const int rl = l & 15;
    const int ql = l >> 4;

    const int srow = tid >> 2;
    const int sk0 = (tid & 3) << 3;
    const int grow = min(bm + srow, M - 1);
    const size_t abase = (size_t)grow * 256 + sk0;

    const size_t boff = (size_t)(w * 64 + rl) * 256 + ql * 8;

    f32x4 acc[4][4];
    #pragma unroll
    for (int i = 0; i < 4; ++i)
        #pragma unroll
        for (int j = 0; j < 4; ++j) acc[i][j] = (f32x4){0.f, 0.f, 0.f, 0.f};

    {
        short8v vh = *(const short8v*)(Ah + abase);
        *(short8v*)&AhS[0][srow][sk0] = vh;
    }
    __syncthreads();

    int buf = 0;
    #pragma unroll
    for (int ks = 0; ks < 8; ++ks) {
        short8v vh;
        const bool pf = ks < 7;
        if (pf) vh = *(const short8v*)(Ah + abase + (ks + 1) * 32);

        short8v bh[4], bl[4];
        #pragma unroll
        for (int nf = 0; nf < 4; ++nf) {
            bh[nf] = *(const short8v*)(Bth + boff + nf * 4096 + ks * 32);
            bl[nf] = *(const short8v*)(Btl + boff + nf * 4096 + ks * 32);
        }
        short8v ah[4];
        #pragma unroll
        for (int mf = 0; mf < 4; ++mf)
            ah[mf] = *(const short8v*)&AhS[buf][mf * 16 + rl][ql * 8];

        #pragma unroll
        for (int mf = 0; mf < 4; ++mf)
            #pragma unroll
            for (int nf = 0; nf < 4; ++nf) {
                acc[mf][nf] = __builtin_amdgcn_mfma_f32_16x16x32_bf16(ah[mf], bh[nf], acc[mf][nf], 0, 0, 0);
                acc[mf][nf] = __builtin_amdgcn_mfma_f32_16x16x32_bf16(ah[mf], bl[nf], acc[mf][nf], 0, 0, 0);
            }
        if (pf) *(short8v*)&AhS[buf ^ 1][srow][sk0] = vh;
        __syncthreads();
        buf ^= 1;
    }

    // epilogue: D col = lane&15, row = (lane>>4)*4 + reg
    #pragma unroll
    for (int mf = 0; mf < 4; ++mf) {
        int row0 = bm + mf * 16 + ql * 4;
        #pragma unroll
        for (int nf = 0; nf < 4; ++nf) {
            int c = w * 64 + nf * 16 + rl;
            #pragma unroll
            for (int j = 0; j < 4; ++j) {
                int r = row0 + j;
                if (r < M) {
                    float v = acc[mf][nf][j];
                    if (mode == 2)
                        ((float*)Cout)[(size_t)r * 256 + c] = tanhf(v);
                    else
                        ((unsigned short*)Cout)[(size_t)r * 256 + c] = bf16_rne(v);
                }
            }
        }
    }
}

// ---------------- K5: per-node top-k + softmax + aggregate ----------------
// 32 lanes per node (2 nodes/wave, 8 nodes/block)
__global__ __launch_bounds__(256) void node_kernel(
    const int* __restrict__ src, const int* __restrict__ relid,
    const float* __restrict__ SS, const double* __restrict__ ssrc0,
    const unsigned short* __restrict__ emb_bf, const unsigned short* __restrict__ rel_bf,
    const float* __restrict__ sr4, const double* __restrict__ sr0,
    unsigned short* __restrict__ nah)
{
    __shared__ __align__(16) float sr4s[N_REL * 4];
    __shared__ double sr0s[N_REL];
    __shared__ float wls[8][32][4];   // unnormalized exp weights per node-in-block
    for (int i = threadIdx.x; i < N_REL; i += 256) {
        *(float4*)&sr4s[i * 4] = *(const float4*)&sr4[i * 4];
        sr0s[i] = sr0[i];
    }
    __syncthreads();

    const int tid = threadIdx.x;
    const int l = tid & 63;
    const int el = l & 31;          // lane within node
    const int hb = l & 32;          // half base (0 or 32)
    const int nib = tid >> 5;       // node in block 0..7
    const int n = blockIdx.x * 8 + nib;

    const int sd_ = src[n * DEG + el];
    const int rd_ = relid[n * DEG + el];
    const double sc0 = ssrc0[sd_] + sr0s[rd_];

    // rank by count among the node's 32 candidates (stable: lower index wins ties)
    int cnt = 0;
    #pragma unroll
    for (int j = 0; j < DEG; ++j) {
        double sj = __shfl(sc0, hb | j);
        cnt += (sj > sc0 || (sj == sc0 && j < el)) ? 1 : 0;
    }
    const bool sel = (cnt < TOPK);
    const unsigned long long mask64 = __ballot(sel);
    const unsigned mask = (unsigned)(mask64 >> hb);

    // f32 scores for selected edges only
    float scx = -1e30f, scy = -1e30f, scz = -1e30f, scw = -1e30f;
    if (sel) {
        float4 ssv = *(const float4*)(SS + (size_t)sd_ * 8);
        float4 srv = *(const float4*)&sr4s[rd_ * 4];
        float4 sdv = *(const float4*)(SS + (size_t)n * 8 + 4);
        scx = leaky(ssv.x + sdv.x + srv.x);
        scy = leaky(ssv.y + sdv.y + srv.y);
        scz = leaky(ssv.z + sdv.z + srv.z);
        scw = leaky(ssv.w + sdv.w + srv.w);
    }

    // butterfly max over 32-lane half
    float mx = scx, my = scy, mz = scz, mw = scw;
    #pragma unroll
    for (int off = 1; off < 32; off <<= 1) {
        mx = fmaxf(mx, __shfl_xor(mx, off));
        my = fmaxf(my, __shfl_xor(my, off));
        mz = fmaxf(mz, __shfl_xor(mz, off));
        mw = fmaxf(mw, __shfl_xor(mw, off));
    }
    float ex = sel ? __expf(scx - mx) : 0.f;
    float ey = sel ? __expf(scy - my) : 0.f;
    float ez = sel ? __expf(scz - mz) : 0.f;
    float ew = sel ? __expf(scw - mw) : 0.f;
    float sx = ex, sy = ey, sz = ez, sw = ew;
    #pragma unroll
    for (int off = 1; off < 32; off <<= 1) {
        sx += __shfl_xor(sx, off);
        sy += __shfl_xor(sy, off);
        sz += __shfl_xor(sz, off);
        sw += __shfl_xor(sw, off);
    }

    if (sel) {
        float4 wv; wv.x = ex; wv.y = ey; wv.z = ez; wv.w = ew;
        *(float4*)&wls[nib][el][0] = wv;
    }
    __syncthreads();

    // aggregation: this lane covers dims el*8 .. el*8+7 (head h) of node n
    const int h = el >> 3;
    const float sh = h == 0 ? sx : h == 1 ? sy : h == 2 ? sz : sw;
    const float rsh = 1.f / sh;

    unsigned mm = mask;
    float acc[8] = {0.f, 0.f, 0.f, 0.f, 0.f, 0.f, 0.f, 0.f};
    #pragma unroll
    for (int t = 0; t < TOPK; ++t) {
        int lk = __builtin_ctz(mm);
        mm &= mm - 1;
        int sk = __shfl(sd_, hb | lk);
        int rk = __shfl(rd_, hb | lk);
        float wgt = wls[nib][lk][h];
        short8v ev = *(const short8v*)(emb_bf + (size_t)sk * 256 + el * 8);
        short8v rv = *(const short8v*)(rel_bf + (size_t)rk * 256 + el * 8);
        #pragma unroll
        for (int j = 0; j < 8; ++j) {
            float e = bf2f((unsigned short)ev[j]);
            float r = bf2f((unsigned short)rv[j]);
            acc[j] += wgt * (e + r);
        }
    }

    unsigned short hh[8];
    #pragma unroll
    for (int j = 0; j < 8; ++j) hh[j] = bf16_rne(acc[j] * rsh);
    short8v ov;
    #pragma unroll
    for (int j = 0; j < 8; ++j) ov[j] = (short)hh[j];
    *(short8v*)(nah + (size_t)n * 256 + el * 8) = ov;
}

extern "C" void kernel_launch(void* const* d_in, const int* in_sizes, int n_in,
                              void* d_out, int out_size, void* d_ws, size_t ws_size,
                              hipStream_t stream) {
    const float* ent  = (const float*)d_in[0];
    const float* rel  = (const float*)d_in[1];
    const float* W    = (const float*)d_in[2];
    const float* W_r  = (const float*)d_in[3];
    const float* a    = (const float*)d_in[4];
    const float* nw   = (const float*)d_in[5];
    const int*   srcp = (const int*)d_in[6];
    const int*   ridp = (const int*)d_in[7];
    float* out = (float*)d_out;

    if (ws_size < WS_NEED) return;

    char* ws = (char*)d_ws;
    double* ssrc0 = (double*)(ws + OFF_SSRC0);
    double* sr0   = (double*)(ws + OFF_SR0);
    double* u0    = (double*)(ws + OFF_U0);
    float*  SS    = (float*)(ws + OFF_SS);
    float*  sr4   = (float*)(ws + OFF_SR4);
    float*  U8    = (float*)(ws + OFF_U8);
    unsigned short* b1h = (unsigned short*)(ws + OFF_B1H);
    unsigned short* b1l = (unsigned short*)(ws + OFF_B1L);
    unsigned short* b2h = (unsigned short*)(ws + OFF_B2H);
    unsigned short* b2l = (unsigned short*)(ws + OFF_B2L);
    unsigned short* eah = (unsigned short*)(ws + OFF_EAH);
    unsigned short* embbf = (unsigned short*)(ws + OFF_EMBBF);
    unsigned short* relbf = (unsigned short*)(ws + OFF_RELBF);
    // neigh-hi aliases ent-hi (dead after gemm1)
    unsigned short* nah = eah;

    setup_kernel<<<382, 256, 0, stream>>>(rel, W_r, W, a, nw,
                                          relbf, sr4, sr0, U8, u0,
                                          b1h, b1l, b2h, b2l);
    ss_kernel<<<512, 256, 0, stream>>>(ent, U8, u0, SS, ssrc0, eah);
    gemm_bs<<<782, 256, 0, stream>>>(eah, b1h, b1l, embbf, N_ENT, 1);
    node_kernel<<<6250, 256, 0, stream>>>(srcp, ridp, SS, ssrc0, embbf, relbf, sr4, sr0, nah);
    gemm_bs<<<782, 256, 0, stream>>>(nah, b2h, b2l, out, N_ENT, 2);
}

// Round 5
// 228.475 us; speedup vs baseline: 1.8469x; 1.0291x over previous
//
#include <hip/hip_runtime.h>
#include <math.h>

#define N_ENT 50000
#define N_REL 500
#define DEG 32
#define TOPK 10
#define H_DIM 256
#define N_HEADS 4
#define HEAD_DIM 64

typedef __attribute__((ext_vector_type(8))) short short8v;
typedef __attribute__((ext_vector_type(4))) float f32x4;

// ---------------- workspace layout (bytes) ----------------
constexpr size_t OFF_SSRC0 = 0;                      // f64 [N_ENT]
constexpr size_t OFF_SR0   = 400000;                 // f64 [N_REL]
constexpr size_t OFF_U0    = 404000;                 // f64 [256]
constexpr size_t OFF_SS    = 406048;                 // f32 [N_ENT][8]
constexpr size_t OFF_SR4   = 2006048;                // f32 [N_REL][4]
constexpr size_t OFF_U8    = 2014048;                // f32 [256][8]
constexpr size_t OFF_B1H   = 2022240;                // bf16 [256][256] x4
constexpr size_t OFF_B1L   = 2153312;
constexpr size_t OFF_B2H   = 2284384;
constexpr size_t OFF_B2L   = 2415456;
constexpr size_t OFF_EAH   = 2546560;                // bf16 [N_ENT][256] (ent hi; later neigh hi)
constexpr size_t OFF_EMBBF = 28146560;               // bf16 [N_ENT][256] emb_t table
constexpr size_t OFF_RELBF = 53746560;               // bf16 [N_REL][256]
constexpr size_t OFF_IDX   = 54002560;               // u32 [N_ENT][10] packed (rel<<16|src)
constexpr size_t OFF_WQ    = 56002560;               // f32 [N_ENT][4][10] normalized weights
constexpr size_t WS_NEED   = 64002560;               // ~61 MB

__device__ __forceinline__ float leaky(float x) { return x >= 0.f ? x : 0.2f * x; }

__device__ __forceinline__ unsigned short bf16_rne(float x) {
    unsigned int u = __float_as_uint(x);
    unsigned int r = u + 0x7fffu + ((u >> 16) & 1u);
    return (unsigned short)(r >> 16);
}
__device__ __forceinline__ float bf2f(unsigned short x) {
    return __uint_as_float((unsigned)x << 16);
}

__device__ __forceinline__ void gload_lds16(const void* g, void* l) {
    __builtin_amdgcn_global_load_lds(
        (const __attribute__((address_space(1))) void*)g,
        (__attribute__((address_space(3))) void*)l, 16, 0, 0);
}

// ---------------- K0: fused setup (rel transform | U vectors | B splits) ----------------
__global__ __launch_bounds__(256) void setup_kernel(
    const float* __restrict__ rel_emb, const float* __restrict__ W_r,
    const float* __restrict__ W, const float* __restrict__ a, const float* __restrict__ nw,
    unsigned short* __restrict__ rel_bf, float* __restrict__ sr4, double* __restrict__ sr0,
    float* __restrict__ U8, double* __restrict__ u0,
    unsigned short* __restrict__ b1h, unsigned short* __restrict__ b1l,
    unsigned short* __restrict__ b2h, unsigned short* __restrict__ b2l)
{
    const int bid = blockIdx.x;
    const int tid = threadIdx.x;
    if (bid < 125) {
        // relation transform: 4 relations per block
        int r = bid * 4 + (tid >> 6);
        int l = tid & 63;
        int h = l >> 4;
        int e4 = (l & 15) << 2;
        const float* Wh = W_r + h * 16384 + e4;

        float ax = 0.f, ay = 0.f, az = 0.f, aw = 0.f;
        double dx = 0.0, dy = 0.0, dz = 0.0, dw = 0.0;
        #pragma unroll 4
        for (int d = 0; d < 256; ++d) {
            float x = rel_emb[r * 256 + d];
            float4 w = *(const float4*)(Wh + d * 64);
            ax += x * w.x; ay += x * w.y; az += x * w.z; aw += x * w.w;
            dx += (double)x * w.x; dy += (double)x * w.y;
            dz += (double)x * w.z; dw += (double)x * w.w;
        }
        uint2 hp;
        hp.x = (unsigned)bf16_rne(ax) | ((unsigned)bf16_rne(ay) << 16);
        hp.y = (unsigned)bf16_rne(az) | ((unsigned)bf16_rne(aw) << 16);
        *(uint2*)(rel_bf + r * 256 + l * 4) = hp;

        const float* ar = a + h * 192 + 128 + e4;
        float s = ax * ar[0] + ay * ar[1] + az * ar[2] + aw * ar[3];
        #pragma unroll
        for (int m = 1; m <= 8; m <<= 1) s += __shfl_xor(s, m);
        if ((l & 15) == 0) sr4[r * 4 + h] = s;

        double sd = dx * (double)a[128 + e4] + dy * (double)a[128 + e4 + 1] +
                    dz * (double)a[128 + e4 + 2] + dw * (double)a[128 + e4 + 3];
        #pragma unroll
        for (int m = 1; m <= 8; m <<= 1) sd += __shfl_xor(sd, m);
        if (l == 0) sr0[r] = sd;
    } else if (bid == 125) {
        // U vectors
        int d = tid;
        for (int h = 0; h < N_HEADS; ++h) {
            float ss = 0.f, sd = 0.f;
            for (int e = 0; e < HEAD_DIM; ++e) {
                float w = W[h * 16384 + d * 64 + e];
                ss += w * a[h * 192 + e];
                sd += w * a[h * 192 + 64 + e];
            }
            U8[d * 8 + h] = ss;
            U8[d * 8 + 4 + h] = sd;
        }
        double s0 = 0.0;
        for (int e = 0; e < HEAD_DIM; ++e)
            s0 += (double)W[d * 64 + e] * (double)a[e];
        u0[d] = s0;
    } else {
        // B splits, transposed [n][k]
        int n = bid - 126;   // output col
        int k = tid;         // inner dim
        int h = n >> 6, e = n & 63;
        float x1 = W[h * 16384 + k * 64 + e];
        float x2 = nw[k * 256 + n];
        unsigned short h1 = bf16_rne(x1);
        unsigned short l1 = bf16_rne(x1 - bf2f(h1));
        unsigned short h2 = bf16_rne(x2);
        unsigned short l2 = bf16_rne(x2 - bf2f(h2));
        b1h[n * 256 + k] = h1; b1l[n * 256 + k] = l1;
        b2h[n * 256 + k] = h2; b2l[n * 256 + k] = l2;
    }
}

// ---------------- K3: SS/ssrc0 + bf16 ent split; 2 rows per wave, U hoisted to regs ----------------
__global__ __launch_bounds__(256) void ss_kernel(
    const float* __restrict__ ent, const float* __restrict__ U8,
    const double* __restrict__ u0,
    float* __restrict__ SS, double* __restrict__ ssrc0,
    unsigned short* __restrict__ eah)
{
    const int tid = threadIdx.x;
    const int l = tid & 63;
    const int el = l & 31;
    const int q2 = l >> 5;

    // hoist this lane's U slice: uu[i][j] = U8[(el*8+i)*8 + j], contiguous 64 f32
    float uu[8][8];
    #pragma unroll
    for (int i = 0; i < 8; ++i) {
        float4 a4 = *(const float4*)(U8 + (el * 8 + i) * 8);
        float4 b4 = *(const float4*)(U8 + (el * 8 + i) * 8 + 4);
        uu[i][0] = a4.x; uu[i][1] = a4.y; uu[i][2] = a4.z; uu[i][3] = a4.w;
        uu[i][4] = b4.x; uu[i][5] = b4.y; uu[i][6] = b4.z; uu[i][7] = b4.w;
    }
    double ud[8];
    #pragma unroll
    for (int i = 0; i < 8; ++i) ud[i] = u0[el * 8 + i];

    int wave = (blockIdx.x * 256 + tid) >> 6;
    int nwaves = gridDim.x * 4;
    for (int p = wave; p < N_ENT / 2; p += nwaves) {
        int n = p * 2 + q2;
        float4 x1 = *(const float4*)(ent + (size_t)n * 256 + el * 8);
        float4 x2 = *(const float4*)(ent + (size_t)n * 256 + el * 8 + 4);
        float xs[8] = {x1.x, x1.y, x1.z, x1.w, x2.x, x2.y, x2.z, x2.w};

        // split-hi write
        unsigned short hh[8];
        #pragma unroll
        for (int i = 0; i < 8; ++i) hh[i] = bf16_rne(xs[i]);
        short8v ov;
        #pragma unroll
        for (int i = 0; i < 8; ++i) ov[i] = (short)hh[i];
        *(short8v*)(eah + (size_t)n * 256 + el * 8) = ov;

        float pj[8] = {0.f, 0.f, 0.f, 0.f, 0.f, 0.f, 0.f, 0.f};
        double pd = 0.0;
        #pragma unroll
        for (int i = 0; i < 8; ++i) {
            #pragma unroll
            for (int j = 0; j < 8; ++j) pj[j] += xs[i] * uu[i][j];
            pd += (double)xs[i] * ud[i];
        }
        #pragma unroll
        for (int off = 1; off < 32; off <<= 1) {
            #pragma unroll
            for (int j = 0; j < 8; ++j) pj[j] += __shfl_xor(pj[j], off);
            pd += __shfl_xor(pd, off);
        }
        if (el == 0) {
            float4 o1; o1.x = pj[0]; o1.y = pj[1]; o1.z = pj[2]; o1.w = pj[3];
            float4 o2; o2.x = pj[4]; o2.y = pj[5]; o2.z = pj[6]; o2.w = pj[7];
            *(float4*)(SS + (size_t)n * 8) = o1;
            *(float4*)(SS + (size_t)n * 8 + 4) = o2;
            ssrc0[n] = pd;
        }
    }
}

// ---------------- K4/K6: bf16 MFMA GEMM, C = Ah @ (Bh+Bl), async A-staging ----------------
// A staged via global_load_lds with XOR-chunk swizzle pre-applied on the global source.
// mode: 1 = bf16 out, 2 = f32 + tanh
__global__ __launch_bounds__(256) void gemm_bs(
    const unsigned short* __restrict__ Ah,
    const unsigned short* __restrict__ Bth, const unsigned short* __restrict__ Btl,
    void* __restrict__ Cout, int M, int mode)
{
    __shared__ unsigned short AhS[2][64][32];   // linear, 4 KB per buffer

    const int tid = threadIdx.x;
    const int l = tid & 63;
    const int w = tid >> 6;
    const int bm = blockIdx.x * 64;
    const int rl = l & 15;
    const int ql = l >> 4;
    const int swz = (rl >> 1) & 3;

    // staging: lane l of wave w covers tile row w*16 + (l>>2), chunk slot l&3
    const int Rtile = w * 16 + (l >> 2);
    const int cslot = l & 3;
    const int g = cslot ^ ((Rtile >> 1) & 3);     // global chunk this slot must hold
    const int grow = min(bm + Rtile, M - 1);
    const unsigned short* gbase = Ah + (size_t)grow * 256 + g * 8;
    char* lslot = ((char*)&AhS[0][0][0]) + (size_t)tid * 16;   // buf0; buf1 at +4096

    const size_t boff = (size_t)(w * 64 + rl) * 256 + ql * 8;

    f32x4 acc[4][4];
    #pragma unroll
    for (int i = 0; i < 4; ++i)
        #pragma unroll
        for (int j = 0; j < 4; ++j) acc[i][j] = (f32x4){0.f, 0.f, 0.f, 0.f};

    gload_lds16(gbase, lslot);          // stage ks=0 into buf0
    __syncthreads();

    int buf = 0;
    #pragma unroll
    for (int ks = 0; ks < 8; ++ks) {
        if (ks < 7)
            gload_lds16(gbase + (ks + 1) * 32, lslot + (buf ^ 1) * 4096);

        short8v bh[4], bl[4];
        #pragma unroll
        for (int nf = 0; nf < 4; ++nf) {
            bh[nf] = *(const short8v*)(Bth + boff + nf * 4096 + ks * 32);
            bl[nf] = *(const short8v*)(Btl + boff + nf * 4096 + ks * 32);
        }
        short8v ah[4];
        #pragma unroll
        for (int mf = 0; mf < 4; ++mf)
            ah[mf] = *(const short8v*)&AhS[buf][mf * 16 + rl][(ql ^ swz) * 8];

        #pragma unroll
        for (int mf = 0; mf < 4; ++mf)
            #pragma unroll
            for (int nf = 0; nf < 4; ++nf) {
                acc[mf][nf] = __builtin_amdgcn_mfma_f32_16x16x32_bf16(ah[mf], bh[nf], acc[mf][nf], 0, 0, 0);
                acc[mf][nf] = __builtin_amdgcn_mfma_f32_16x16x32_bf16(ah[mf], bl[nf], acc[mf][nf], 0, 0, 0);
            }
        __syncthreads();                 // drains prefetch (vmcnt) + protects LDS reuse
        buf ^= 1;
    }

    // epilogue: D col = lane&15, row = (lane>>4)*4 + reg
    #pragma unroll
    for (int mf = 0; mf < 4; ++mf) {
        int row0 = bm + mf * 16 + ql * 4;
        #pragma unroll
        for (int nf = 0; nf < 4; ++nf) {
            int c = w * 64 + nf * 16 + rl;
            #pragma unroll
            for (int j = 0; j < 4; ++j) {
                int r = row0 + j;
                if (r < M) {
                    float v = acc[mf][nf][j];
                    if (mode == 2)
                        ((float*)Cout)[(size_t)r * 256 + c] = tanhf(v);
                    else
                        ((unsigned short*)Cout)[(size_t)r * 256 + c] = bf16_rne(v);
                }
            }
        }
    }
}

// ---------------- K5a: top-k select + softmax weights (no gathers of emb/rel) ----------------
// 32 lanes per node, 8 nodes per block
__global__ __launch_bounds__(256) void select_kernel(
    const int* __restrict__ src, const int* __restrict__ relid,
    const float* __restrict__ SS, const double* __restrict__ ssrc0,
    const float* __restrict__ sr4, const double* __restrict__ sr0,
    unsigned* __restrict__ idxp, float* __restrict__ wq)
{
    __shared__ __align__(16) float sr4s[N_REL * 4];
    __shared__ double sr0s[N_REL];
    for (int i = threadIdx.x; i < N_REL; i += 256) {
        *(float4*)&sr4s[i * 4] = *(const float4*)&sr4[i * 4];
        sr0s[i] = sr0[i];
    }
    __syncthreads();

    const int tid = threadIdx.x;
    const int l = tid & 63;
    const int el = l & 31;
    const int hb = l & 32;
    const int n = blockIdx.x * 8 + (tid >> 5);

    const int sd_ = src[n * DEG + el];
    const int rd_ = relid[n * DEG + el];
    const double sc0 = ssrc0[sd_] + sr0s[rd_];

    // rank by count (stable: lower index wins ties)
    int cnt = 0;
    #pragma unroll
    for (int j = 0; j < DEG; ++j) {
        double sj = __shfl(sc0, hb | j);
        cnt += (sj > sc0 || (sj == sc0 && j < el)) ? 1 : 0;
    }
    const bool sel = (cnt < TOPK);
    const unsigned mask = (unsigned)(__ballot(sel) >> hb);

    float scx = -1e30f, scy = -1e30f, scz = -1e30f, scw = -1e30f;
    if (sel) {
        float4 ssv = *(const float4*)(SS + (size_t)sd_ * 8);
        float4 srv = *(const float4*)&sr4s[rd_ * 4];
        float4 sdv = *(const float4*)(SS + (size_t)n * 8 + 4);
        scx = leaky(ssv.x + sdv.x + srv.x);
        scy = leaky(ssv.y + sdv.y + srv.y);
        scz = leaky(ssv.z + sdv.z + srv.z);
        scw = leaky(ssv.w + sdv.w + srv.w);
    }

    float mx = scx, my = scy, mz = scz, mw = scw;
    #pragma unroll
    for (int off = 1; off < 32; off <<= 1) {
        mx = fmaxf(mx, __shfl_xor(mx, off));
        my = fmaxf(my, __shfl_xor(my, off));
        mz = fmaxf(mz, __shfl_xor(mz, off));
        mw = fmaxf(mw, __shfl_xor(mw, off));
    }
    float ex = sel ? __expf(scx - mx) : 0.f;
    float ey = sel ? __expf(scy - my) : 0.f;
    float ez = sel ? __expf(scz - mz) : 0.f;
    float ew = sel ? __expf(scw - mw) : 0.f;
    float sx = ex, sy = ey, sz = ez, sw = ew;
    #pragma unroll
    for (int off = 1; off < 32; off <<= 1) {
        sx += __shfl_xor(sx, off);
        sy += __shfl_xor(sy, off);
        sz += __shfl_xor(sz, off);
        sw += __shfl_xor(sw, off);
    }

    if (sel) {
        int pos = __popc(mask & ((1u << el) - 1u));
        idxp[n * TOPK + pos] = (unsigned)sd_ | ((unsigned)rd_ << 16);
        float* wqn = wq + (size_t)n * 40;
        wqn[0 * TOPK + pos] = ex / sx;
        wqn[1 * TOPK + pos] = ey / sy;
        wqn[2 * TOPK + pos] = ez / sz;
        wqn[3 * TOPK + pos] = ew / sw;
    }
}

// ---------------- K5b: gather-aggregate (pure memory kernel) ----------------
// 32 lanes per node (8 dims/lane), 8 nodes per block
__global__ __launch_bounds__(256) void aggr_kernel(
    const unsigned* __restrict__ idxp, const float* __restrict__ wq,
    const unsigned short* __restrict__ emb_bf, const unsigned short* __restrict__ rel_bf,
    unsigned short* __restrict__ nah)
{
    const int tid = threadIdx.x;
    const int el = tid & 31;
    const int n = blockIdx.x * 8 + (tid >> 5);
    const int h = el >> 3;

    unsigned id[TOPK];
    float wgt[TOPK];
    const unsigned* ip = idxp + (size_t)n * TOPK;
    const float* wp = wq + (size_t)n * 40 + h * TOPK;
    #pragma unroll
    for (int k = 0; k < TOPK; ++k) id[k] = ip[k];
    #pragma unroll
    for (int k = 0; k < TOPK; ++k) wgt[k] = wp[k];

    float acc[8] = {0.f, 0.f, 0.f, 0.f, 0.f, 0.f, 0.f, 0.f};
    #pragma unroll
    for (int k = 0; k < TOPK; ++k) {
        int sk = id[k] & 0xFFFF;
        int rk = id[k] >> 16;
        short8v ev = *(const short8v*)(emb_bf + (size_t)sk * 256 + el * 8);
        short8v rv = *(const short8v*)(rel_bf + (size_t)rk * 256 + el * 8);
        float w = wgt[k];
        #pragma unroll
        for (int j = 0; j < 8; ++j)
            acc[j] += w * (bf2f((unsigned short)ev[j]) + bf2f((unsigned short)rv[j]));
    }

    short8v ov;
    #pragma unroll
    for (int j = 0; j < 8; ++j) ov[j] = (short)bf16_rne(acc[j]);
    *(short8v*)(nah + (size_t)n * 256 + el * 8) = ov;
}

extern "C" void kernel_launch(void* const* d_in, const int* in_sizes, int n_in,
                              void* d_out, int out_size, void* d_ws, size_t ws_size,
                              hipStream_t stream) {
    const float* ent  = (const float*)d_in[0];
    const float* rel  = (const float*)d_in[1];
    const float* W    = (const float*)d_in[2];
    const float* W_r  = (const float*)d_in[3];
    const float* a    = (const float*)d_in[4];
    const float* nw   = (const float*)d_in[5];
    const int*   srcp = (const int*)d_in[6];
    const int*   ridp = (const int*)d_in[7];
    float* out = (float*)d_out;

    if (ws_size < WS_NEED) return;

    char* ws = (char*)d_ws;
    double* ssrc0 = (double*)(ws + OFF_SSRC0);
    double* sr0   = (double*)(ws + OFF_SR0);
    double* u0    = (double*)(ws + OFF_U0);
    float*  SS    = (float*)(ws + OFF_SS);
    float*  sr4   = (float*)(ws + OFF_SR4);
    float*  U8    = (float*)(ws + OFF_U8);
    unsigned short* b1h = (unsigned short*)(ws + OFF_B1H);
    unsigned short* b1l = (unsigned short*)(ws + OFF_B1L);
    unsigned short* b2h = (unsigned short*)(ws + OFF_B2H);
    unsigned short* b2l = (unsigned short*)(ws + OFF_B2L);
    unsigned short* eah = (unsigned short*)(ws + OFF_EAH);
    unsigned short* embbf = (unsigned short*)(ws + OFF_EMBBF);
    unsigned short* relbf = (unsigned short*)(ws + OFF_RELBF);
    unsigned* idxp = (unsigned*)(ws + OFF_IDX);
    float*    wqp  = (float*)(ws + OFF_WQ);
    // neigh-hi aliases ent-hi (dead after gemm1)
    unsigned short* nah = eah;

    setup_kernel<<<382, 256, 0, stream>>>(rel, W_r, W, a, nw,
                                          relbf, sr4, sr0, U8, u0,
                                          b1h, b1l, b2h, b2l);
    ss_kernel<<<512, 256, 0, stream>>>(ent, U8, u0, SS, ssrc0, eah);
    select_kernel<<<6250, 256, 0, stream>>>(srcp, ridp, SS, ssrc0, sr4, sr0, idxp, wqp);
    gemm_bs<<<782, 256, 0, stream>>>(eah, b1h, b1l, embbf, N_ENT, 1);
    aggr_kernel<<<6250, 256, 0, stream>>>(idxp, wqp, embbf, relbf, nah);
    gemm_bs<<<782, 256, 0, stream>>>(nah, b2h, b2l, out, N_ENT, 2);
}

// Round 6
// 194.745 us; speedup vs baseline: 2.1668x; 1.1732x over previous
//
#include <hip/hip_runtime.h>
#include <math.h>

#define N_ENT 50000
#define N_REL 500
#define DEG 32
#define TOPK 10
#define H_DIM 256
#define N_HEADS 4
#define HEAD_DIM 64

typedef __attribute__((ext_vector_type(8))) short short8v;
typedef __attribute__((ext_vector_type(4))) float f32x4;

// ---------------- workspace layout (bytes) ----------------
constexpr size_t OFF_SSRC0 = 0;                      // f64 [N_ENT]
constexpr size_t OFF_SR0   = 400000;                 // f64 [N_REL]
constexpr size_t OFF_U0    = 404000;                 // f64 [256]
constexpr size_t OFF_SS    = 406048;                 // f32 [N_ENT][8]
constexpr size_t OFF_SR4   = 2006048;                // f32 [N_REL][4]
constexpr size_t OFF_U8    = 2014048;                // f32 [256][8]
constexpr size_t OFF_B1H   = 2022240;                // bf16 packed [16][8][64][8] x4
constexpr size_t OFF_B1L   = 2153312;
constexpr size_t OFF_B2H   = 2284384;
constexpr size_t OFF_B2L   = 2415456;
constexpr size_t OFF_EAH   = 2546560;                // bf16 packed A (ent hi; later neigh hi), 25.7 MB
constexpr size_t OFF_EMBBF = 28246560;               // bf16 [N_ENT][256] emb_t table (row-major)
constexpr size_t OFF_RELBF = 53846560;               // bf16 [N_REL][256]
constexpr size_t OFF_IDX   = 54102560;               // u32 [N_ENT][10] packed (rel<<16|src)
constexpr size_t OFF_WQ    = 56102560;               // f32 [N_ENT][4][10] normalized weights
constexpr size_t WS_NEED   = 64102560;               // ~61 MB

__device__ __forceinline__ float leaky(float x) { return x >= 0.f ? x : 0.2f * x; }

__device__ __forceinline__ unsigned short bf16_rne(float x) {
    unsigned int u = __float_as_uint(x);
    unsigned int r = u + 0x7fffu + ((u >> 16) & 1u);
    return (unsigned short)(r >> 16);
}
__device__ __forceinline__ float bf2f(unsigned short x) {
    return __uint_as_float((unsigned)x << 16);
}

// MFMA-fragment pack offset for element (row, d) of a [R][256] bf16 matrix:
// off = ((row>>4)*8 + (d>>5))*512 + (((d>>3)&3)*16 + (row&15))*8 + (d&7)
// so that lane l (=ql*16+rl) of a wave reads frag (g16, ks) as 8 contiguous
// shorts at base + (g16*8 + ks)*512 + l*8  -> one 1KB coalesced load/wave.
__device__ __forceinline__ size_t pack_off(int row, int d) {
    return ((size_t)(row >> 4) * 8 + (d >> 5)) * 512 +
           (((d >> 3) & 3) * 16 + (row & 15)) * 8 + (d & 7);
}

// ---------------- K0: fused setup (rel transform | U vectors | B splits) ----------------
__global__ __launch_bounds__(256) void setup_kernel(
    const float* __restrict__ rel_emb, const float* __restrict__ W_r,
    const float* __restrict__ W, const float* __restrict__ a, const float* __restrict__ nw,
    unsigned short* __restrict__ rel_bf, float* __restrict__ sr4, double* __restrict__ sr0,
    float* __restrict__ U8, double* __restrict__ u0,
    unsigned short* __restrict__ b1h, unsigned short* __restrict__ b1l,
    unsigned short* __restrict__ b2h, unsigned short* __restrict__ b2l)
{
    const int bid = blockIdx.x;
    const int tid = threadIdx.x;
    if (bid < 125) {
        // relation transform: 4 relations per block
        int r = bid * 4 + (tid >> 6);
        int l = tid & 63;
        int h = l >> 4;
        int e4 = (l & 15) << 2;
        const float* Wh = W_r + h * 16384 + e4;

        float ax = 0.f, ay = 0.f, az = 0.f, aw = 0.f;
        double dx = 0.0, dy = 0.0, dz = 0.0, dw = 0.0;
        #pragma unroll 4
        for (int d = 0; d < 256; ++d) {
            float x = rel_emb[r * 256 + d];
            float4 w = *(const float4*)(Wh + d * 64);
            ax += x * w.x; ay += x * w.y; az += x * w.z; aw += x * w.w;
            dx += (double)x * w.x; dy += (double)x * w.y;
            dz += (double)x * w.z; dw += (double)x * w.w;
        }
        uint2 hp;
        hp.x = (unsigned)bf16_rne(ax) | ((unsigned)bf16_rne(ay) << 16);
        hp.y = (unsigned)bf16_rne(az) | ((unsigned)bf16_rne(aw) << 16);
        *(uint2*)(rel_bf + r * 256 + l * 4) = hp;

        const float* ar = a + h * 192 + 128 + e4;
        float s = ax * ar[0] + ay * ar[1] + az * ar[2] + aw * ar[3];
        #pragma unroll
        for (int m = 1; m <= 8; m <<= 1) s += __shfl_xor(s, m);
        if ((l & 15) == 0) sr4[r * 4 + h] = s;

        double sd = dx * (double)a[128 + e4] + dy * (double)a[128 + e4 + 1] +
                    dz * (double)a[128 + e4 + 2] + dw * (double)a[128 + e4 + 3];
        #pragma unroll
        for (int m = 1; m <= 8; m <<= 1) sd += __shfl_xor(sd, m);
        if (l == 0) sr0[r] = sd;
    } else if (bid == 125) {
        // U vectors
        int d = tid;
        for (int h = 0; h < N_HEADS; ++h) {
            float ss = 0.f, sd = 0.f;
            for (int e = 0; e < HEAD_DIM; ++e) {
                float w = W[h * 16384 + d * 64 + e];
                ss += w * a[h * 192 + e];
                sd += w * a[h * 192 + 64 + e];
            }
            U8[d * 8 + h] = ss;
            U8[d * 8 + 4 + h] = sd;
        }
        double s0 = 0.0;
        for (int e = 0; e < HEAD_DIM; ++e)
            s0 += (double)W[d * 64 + e] * (double)a[e];
        u0[d] = s0;
    } else {
        // B splits, packed fragment layout. col n, inner k.
        int n = bid - 126;   // output col
        int k = tid;         // inner dim
        int h = n >> 6, e = n & 63;
        float x1 = W[h * 16384 + k * 64 + e];
        float x2 = nw[k * 256 + n];
        unsigned short h1 = bf16_rne(x1);
        unsigned short l1 = bf16_rne(x1 - bf2f(h1));
        unsigned short h2 = bf16_rne(x2);
        unsigned short l2 = bf16_rne(x2 - bf2f(h2));
        size_t off = pack_off(n, k);
        b1h[off] = h1; b1l[off] = l1;
        b2h[off] = h2; b2l[off] = l2;
    }
}

// ---------------- K3: SS/ssrc0 + packed bf16 ent split ----------------
__global__ __launch_bounds__(256) void ss_kernel(
    const float* __restrict__ ent, const float* __restrict__ U8,
    const double* __restrict__ u0,
    float* __restrict__ SS, double* __restrict__ ssrc0,
    unsigned short* __restrict__ apk)
{
    const int tid = threadIdx.x;
    const int l = tid & 63;
    const int el = l & 31;
    const int q2 = l >> 5;

    // hoist this lane's U slice
    float uu[8][8];
    #pragma unroll
    for (int i = 0; i < 8; ++i) {
        float4 a4 = *(const float4*)(U8 + (el * 8 + i) * 8);
        float4 b4 = *(const float4*)(U8 + (el * 8 + i) * 8 + 4);
        uu[i][0] = a4.x; uu[i][1] = a4.y; uu[i][2] = a4.z; uu[i][3] = a4.w;
        uu[i][4] = b4.x; uu[i][5] = b4.y; uu[i][6] = b4.z; uu[i][7] = b4.w;
    }
    double ud[8];
    #pragma unroll
    for (int i = 0; i < 8; ++i) ud[i] = u0[el * 8 + i];

    int wave = (blockIdx.x * 256 + tid) >> 6;
    int nwaves = gridDim.x * 4;
    for (int p = wave; p < N_ENT / 2; p += nwaves) {
        int n = p * 2 + q2;
        float4 x1 = *(const float4*)(ent + (size_t)n * 256 + el * 8);
        float4 x2 = *(const float4*)(ent + (size_t)n * 256 + el * 8 + 4);
        float xs[8] = {x1.x, x1.y, x1.z, x1.w, x2.x, x2.y, x2.z, x2.w};

        // packed split-hi write (dims el*8 .. el*8+7 stay contiguous)
        short8v ov;
        #pragma unroll
        for (int i = 0; i < 8; ++i) ov[i] = (short)bf16_rne(xs[i]);
        *(short8v*)(apk + pack_off(n, el * 8)) = ov;

        float pj[8] = {0.f, 0.f, 0.f, 0.f, 0.f, 0.f, 0.f, 0.f};
        double pd = 0.0;
        #pragma unroll
        for (int i = 0; i < 8; ++i) {
            #pragma unroll
            for (int j = 0; j < 8; ++j) pj[j] += xs[i] * uu[i][j];
            pd += (double)xs[i] * ud[i];
        }
        #pragma unroll
        for (int off = 1; off < 32; off <<= 1) {
            #pragma unroll
            for (int j = 0; j < 8; ++j) pj[j] += __shfl_xor(pj[j], off);
            pd += __shfl_xor(pd, off);
        }
        if (el == 0) {
            float4 o1; o1.x = pj[0]; o1.y = pj[1]; o1.z = pj[2]; o1.w = pj[3];
            float4 o2; o2.x = pj[4]; o2.y = pj[5]; o2.z = pj[6]; o2.w = pj[7];
            *(float4*)(SS + (size_t)n * 8) = o1;
            *(float4*)(SS + (size_t)n * 8 + 4) = o2;
            ssrc0[n] = pd;
        }
    }
}

// ---------------- K4/K6: packed-fragment MFMA GEMM, no LDS, no barriers ----------------
// C[M,256] = A @ (Bh+Bl); all operands pre-packed in fragment order.
// mode: 1 = bf16 out (row-major), 2 = f32 + tanh
__global__ __launch_bounds__(256, 4) void gemm_pk(
    const unsigned short* __restrict__ Apk,
    const unsigned short* __restrict__ Bpkh, const unsigned short* __restrict__ Bpkl,
    void* __restrict__ Cout, int M, int mode)
{
    const int tid = threadIdx.x;
    const int l = tid & 63;
    const int w = tid >> 6;
    const int bm = blockIdx.x * 64;
    const int rl = l & 15;
    const int ql = l >> 4;

    const unsigned short* ab = Apk + (size_t)(bm >> 4) * 4096 + l * 8;
    const unsigned short* bhb = Bpkh + (size_t)w * 16384 + l * 8;
    const unsigned short* blb = Bpkl + (size_t)w * 16384 + l * 8;

    f32x4 acc[4][4];
    #pragma unroll
    for (int i = 0; i < 4; ++i)
        #pragma unroll
        for (int j = 0; j < 4; ++j) acc[i][j] = (f32x4){0.f, 0.f, 0.f, 0.f};

    #pragma unroll 2
    for (int ks = 0; ks < 8; ++ks) {
        short8v ah[4], bh[4], bl[4];
        #pragma unroll
        for (int mf = 0; mf < 4; ++mf)
            ah[mf] = *(const short8v*)(ab + mf * 4096 + ks * 512);
        #pragma unroll
        for (int nf = 0; nf < 4; ++nf) {
            bh[nf] = *(const short8v*)(bhb + nf * 4096 + ks * 512);
            bl[nf] = *(const short8v*)(blb + nf * 4096 + ks * 512);
        }
        #pragma unroll
        for (int mf = 0; mf < 4; ++mf)
            #pragma unroll
            for (int nf = 0; nf < 4; ++nf) {
                acc[mf][nf] = __builtin_amdgcn_mfma_f32_16x16x32_bf16(ah[mf], bh[nf], acc[mf][nf], 0, 0, 0);
                acc[mf][nf] = __builtin_amdgcn_mfma_f32_16x16x32_bf16(ah[mf], bl[nf], acc[mf][nf], 0, 0, 0);
            }
    }

    // epilogue: D col = lane&15, row = (lane>>4)*4 + reg
    #pragma unroll
    for (int mf = 0; mf < 4; ++mf) {
        int row0 = bm + mf * 16 + ql * 4;
        #pragma unroll
        for (int nf = 0; nf < 4; ++nf) {
            int c = w * 64 + nf * 16 + rl;
            #pragma unroll
            for (int j = 0; j < 4; ++j) {
                int r = row0 + j;
                if (r < M) {
                    float v = acc[mf][nf][j];
                    if (mode == 2)
                        ((float*)Cout)[(size_t)r * 256 + c] =
                            1.f - 2.f / (__expf(2.f * v) + 1.f);
                    else
                        ((unsigned short*)Cout)[(size_t)r * 256 + c] = bf16_rne(v);
                }
            }
        }
    }
}

// ---------------- K5a: top-k select + softmax weights ----------------
// 32 lanes per node, 8 nodes per block
__global__ __launch_bounds__(256) void select_kernel(
    const int* __restrict__ src, const int* __restrict__ relid,
    const float* __restrict__ SS, const double* __restrict__ ssrc0,
    const float* __restrict__ sr4, const double* __restrict__ sr0,
    unsigned* __restrict__ idxp, float* __restrict__ wq)
{
    __shared__ __align__(16) float sr4s[N_REL * 4];
    __shared__ double sr0s[N_REL];
    for (int i = threadIdx.x; i < N_REL; i += 256) {
        *(float4*)&sr4s[i * 4] = *(const float4*)&sr4[i * 4];
        sr0s[i] = sr0[i];
    }
    __syncthreads();

    const int tid = threadIdx.x;
    const int l = tid & 63;
    const int el = l & 31;
    const int hb = l & 32;
    const int n = blockIdx.x * 8 + (tid >> 5);

    const int sd_ = src[n * DEG + el];
    const int rd_ = relid[n * DEG + el];
    const double sc0 = ssrc0[sd_] + sr0s[rd_];

    // rank by count (stable: lower index wins ties)
    int cnt = 0;
    #pragma unroll
    for (int j = 0; j < DEG; ++j) {
        double sj = __shfl(sc0, hb | j);
        cnt += (sj > sc0 || (sj == sc0 && j < el)) ? 1 : 0;
    }
    const bool sel = (cnt < TOPK);
    const unsigned mask = (unsigned)(__ballot(sel) >> hb);

    float scx = -1e30f, scy = -1e30f, scz = -1e30f, scw = -1e30f;
    if (sel) {
        float4 ssv = *(const float4*)(SS + (size_t)sd_ * 8);
        float4 srv = *(const float4*)&sr4s[rd_ * 4];
        float4 sdv = *(const float4*)(SS + (size_t)n * 8 + 4);
        scx = leaky(ssv.x + sdv.x + srv.x);
        scy = leaky(ssv.y + sdv.y + srv.y);
        scz = leaky(ssv.z + sdv.z + srv.z);
        scw = leaky(ssv.w + sdv.w + srv.w);
    }

    float mx = scx, my = scy, mz = scz, mw = scw;
    #pragma unroll
    for (int off = 1; off < 32; off <<= 1) {
        mx = fmaxf(mx, __shfl_xor(mx, off));
        my = fmaxf(my, __shfl_xor(my, off));
        mz = fmaxf(mz, __shfl_xor(mz, off));
        mw = fmaxf(mw, __shfl_xor(mw, off));
    }
    float ex = sel ? __expf(scx - mx) : 0.f;
    float ey = sel ? __expf(scy - my) : 0.f;
    float ez = sel ? __expf(scz - mz) : 0.f;
    float ew = sel ? __expf(scw - mw) : 0.f;
    float sx = ex, sy = ey, sz = ez, sw = ew;
    #pragma unroll
    for (int off = 1; off < 32; off <<= 1) {
        sx += __shfl_xor(sx, off);
        sy += __shfl_xor(sy, off);
        sz += __shfl_xor(sz, off);
        sw += __shfl_xor(sw, off);
    }

    if (sel) {
        int pos = __popc(mask & ((1u << el) - 1u));
        idxp[n * TOPK + pos] = (unsigned)sd_ | ((unsigned)rd_ << 16);
        float* wqn = wq + (size_t)n * 40;
        wqn[0 * TOPK + pos] = ex / sx;
        wqn[1 * TOPK + pos] = ey / sy;
        wqn[2 * TOPK + pos] = ez / sz;
        wqn[3 * TOPK + pos] = ew / sw;
    }
}

// ---------------- K5b: gather-aggregate (pure memory kernel) ----------------
// 32 lanes per node (8 dims/lane), 8 nodes per block; packed output
__global__ __launch_bounds__(256) void aggr_kernel(
    const unsigned* __restrict__ idxp, const float* __restrict__ wq,
    const unsigned short* __restrict__ emb_bf, const unsigned short* __restrict__ rel_bf,
    unsigned short* __restrict__ napk)
{
    const int tid = threadIdx.x;
    const int el = tid & 31;
    const int n = blockIdx.x * 8 + (tid >> 5);
    const int h = el >> 3;

    unsigned id[TOPK];
    float wgt[TOPK];
    const unsigned* ip = idxp + (size_t)n * TOPK;
    const float* wp = wq + (size_t)n * 40 + h * TOPK;
    #pragma unroll
    for (int k = 0; k < TOPK; ++k) id[k] = ip[k];
    #pragma unroll
    for (int k = 0; k < TOPK; ++k) wgt[k] = wp[k];

    float acc[8] = {0.f, 0.f, 0.f, 0.f, 0.f, 0.f, 0.f, 0.f};
    #pragma unroll
    for (int k = 0; k < TOPK; ++k) {
        int sk = id[k] & 0xFFFF;
        int rk = id[k] >> 16;
        short8v ev = *(const short8v*)(emb_bf + (size_t)sk * 256 + el * 8);
        short8v rv = *(const short8v*)(rel_bf + (size_t)rk * 256 + el * 8);
        float w = wgt[k];
        #pragma unroll
        for (int j = 0; j < 8; ++j)
            acc[j] += w * (bf2f((unsigned short)ev[j]) + bf2f((unsigned short)rv[j]));
    }

    short8v ov;
    #pragma unroll
    for (int j = 0; j < 8; ++j) ov[j] = (short)bf16_rne(acc[j]);
    *(short8v*)(napk + pack_off(n, el * 8)) = ov;
}

extern "C" void kernel_launch(void* const* d_in, const int* in_sizes, int n_in,
                              void* d_out, int out_size, void* d_ws, size_t ws_size,
                              hipStream_t stream) {
    const float* ent  = (const float*)d_in[0];
    const float* rel  = (const float*)d_in[1];
    const float* W    = (const float*)d_in[2];
    const float* W_r  = (const float*)d_in[3];
    const float* a    = (const float*)d_in[4];
    const float* nw   = (const float*)d_in[5];
    const int*   srcp = (const int*)d_in[6];
    const int*   ridp = (const int*)d_in[7];
    float* out = (float*)d_out;

    if (ws_size < WS_NEED) return;

    char* ws = (char*)d_ws;
    double* ssrc0 = (double*)(ws + OFF_SSRC0);
    double* sr0   = (double*)(ws + OFF_SR0);
    double* u0    = (double*)(ws + OFF_U0);
    float*  SS    = (float*)(ws + OFF_SS);
    float*  sr4   = (float*)(ws + OFF_SR4);
    float*  U8    = (float*)(ws + OFF_U8);
    unsigned short* b1h = (unsigned short*)(ws + OFF_B1H);
    unsigned short* b1l = (unsigned short*)(ws + OFF_B1L);
    unsigned short* b2h = (unsigned short*)(ws + OFF_B2H);
    unsigned short* b2l = (unsigned short*)(ws + OFF_B2L);
    unsigned short* apk = (unsigned short*)(ws + OFF_EAH);
    unsigned short* embbf = (unsigned short*)(ws + OFF_EMBBF);
    unsigned short* relbf = (unsigned short*)(ws + OFF_RELBF);
    unsigned* idxp = (unsigned*)(ws + OFF_IDX);
    float*    wqp  = (float*)(ws + OFF_WQ);
    // neigh-packed aliases ent-packed (dead after gemm1)
    unsigned short* napk = apk;

    setup_kernel<<<382, 256, 0, stream>>>(rel, W_r, W, a, nw,
                                          relbf, sr4, sr0, U8, u0,
                                          b1h, b1l, b2h, b2l);
    ss_kernel<<<512, 256, 0, stream>>>(ent, U8, u0, SS, ssrc0, apk);
    select_kernel<<<6250, 256, 0, stream>>>(srcp, ridp, SS, ssrc0, sr4, sr0, idxp, wqp);
    gemm_pk<<<782, 256, 0, stream>>>(apk, b1h, b1l, embbf, N_ENT, 1);
    aggr_kernel<<<6250, 256, 0, stream>>>(idxp, wqp, embbf, relbf, napk);
    gemm_pk<<<782, 256, 0, stream>>>(napk, b2h, b2l, out, N_ENT, 2);
}